// Round 2
// baseline (5815.368 us; speedup 1.0000x reference)
//
#include <hip/hip_runtime.h>
#include <hip/hip_bf16.h>

__device__ __forceinline__ void ld4(const float* p, float& a,float& b,float& c,float& d){
  float4 v = *reinterpret_cast<const float4*>(p); a=v.x; b=v.y; c=v.z; d=v.w;
}

__device__ __forceinline__ float wave_sum(float v){
  #pragma unroll
  for (int off=32; off>0; off>>=1) v += __shfl_down(v, off);
  return v;
}
__device__ __forceinline__ float wave_max(float v){
  #pragma unroll
  for (int off=32; off>0; off>>=1) v = fmaxf(v, __shfl_down(v, off));
  return v;
}

// ---------------- row LayerNorm ----------------
__global__ __launch_bounds__(256) void ln_rows(const float* __restrict__ in,
    const float* __restrict__ g, const float* __restrict__ b,
    float* __restrict__ out){
  int row = blockIdx.x;
  const float* x = in + (size_t)row*768;
  float* o = out + (size_t)row*768;
  float s=0.f, s2=0.f;
  for (int d=threadIdx.x; d<768; d+=256){ float v=x[d]; s+=v; s2+=v*v; }
  s = wave_sum(s); s2 = wave_sum(s2);
  __shared__ float red[8];
  __shared__ float stat[2];
  int lane = threadIdx.x & 63, wid = threadIdx.x >> 6;
  if (lane==0){ red[wid]=s; red[4+wid]=s2; }
  __syncthreads();
  if (threadIdx.x==0){
    float S=red[0]+red[1]+red[2]+red[3];
    float S2=red[4]+red[5]+red[6]+red[7];
    float m = S*(1.f/768.f);
    float var = S2*(1.f/768.f) - m*m;
    stat[0]=m; stat[1]=rsqrtf(var + 1e-5f);
  }
  __syncthreads();
  float m=stat[0], inv=stat[1];
  for (int d=threadIdx.x; d<768; d+=256)
    o[d] = (x[d]-m)*inv*g[d] + b[d];
}

// ---------------- router: softmax( X @ W^T + b ) over 5 experts ----------------
__global__ __launch_bounds__(64) void router(const float* __restrict__ X,
    const float* __restrict__ W, const float* __restrict__ bias,
    float* __restrict__ out, int K){
  int row = blockIdx.x, lane = threadIdx.x;
  const float* x = X + (size_t)row*K;
  float lg[5];
  #pragma unroll
  for (int e=0;e<5;++e){
    const float* w = W + (size_t)e*K;
    float p=0.f;
    for (int d=lane; d<K; d+=64) p += x[d]*w[d];
    lg[e] = wave_sum(p);
  }
  if (lane==0){
    float mx=-1e30f;
    #pragma unroll
    for (int e=0;e<5;++e){ lg[e] += bias[e]; mx = fmaxf(mx, lg[e]); }
    float s=0.f;
    #pragma unroll
    for (int e=0;e<5;++e){ lg[e]=expf(lg[e]-mx); s+=lg[e]; }
    float inv=1.f/s;
    #pragma unroll
    for (int e=0;e<5;++e) out[(size_t)row*5+e] = lg[e]*inv;
  }
}

// ---------------- msg attention: seq=8 within each b, 12 heads ----------------
__global__ __launch_bounds__(64) void msg_attn(const float* __restrict__ mqkv,
    float* __restrict__ mattno){
  int bh = blockIdx.x; int b = bh/12, h = bh%12;
  __shared__ float qs[8][64], ks[8][64], vs[8][64], sc[8][8];
  int lane = threadIdx.x;
  for (int i=lane; i<512; i+=64){
    int t=i>>6, d=i&63;
    size_t base = ((size_t)(b*8+t))*2304 + h*64 + d;
    qs[t][d]=mqkv[base]; ks[t][d]=mqkv[base+768]; vs[t][d]=mqkv[base+1536];
  }
  __syncthreads();
  { int t=lane>>3, m=lane&7; float a=0.f;
    #pragma unroll
    for (int d=0;d<64;++d) a += qs[t][d]*ks[m][d];
    sc[t][m] = a*0.125f; }
  __syncthreads();
  if (lane<8){
    int t=lane; float mx=-1e30f;
    #pragma unroll
    for (int m=0;m<8;++m) mx=fmaxf(mx, sc[t][m]);
    float s=0.f;
    #pragma unroll
    for (int m=0;m<8;++m){ float e=expf(sc[t][m]-mx); sc[t][m]=e; s+=e; }
    float inv=1.f/s;
    #pragma unroll
    for (int m=0;m<8;++m) sc[t][m]*=inv;
  }
  __syncthreads();
  { int t=lane>>3, d0=(lane&7)*8;
    for (int dd=0; dd<8; ++dd){
      int d=d0+dd; float a=0.f;
      #pragma unroll
      for (int m=0;m<8;++m) a += sc[t][m]*vs[m][d];
      mattno[((size_t)(b*8+t))*768 + h*64 + d] = a;
    } }
}

// ---------------- main attention: seq=198, batch=32, 12 heads ----------------
__global__ __launch_bounds__(256) void attn198(const float* __restrict__ qkv,
    float* __restrict__ attno){
  int bh = blockIdx.x; int bb = bh/12, h = bh%12;
  int l0 = blockIdx.y*8;
  __shared__ float Ks[198*65];
  __shared__ float qs[8][64];
  __shared__ float ps[8][200];
  __shared__ float red[2];
  int tid = threadIdx.x;
  for (int i=tid; i<198*64; i+=256){
    int m=i>>6, d=i&63;
    Ks[m*65+d] = qkv[((size_t)(m*32+bb))*2304 + 768 + h*64 + d];
  }
  for (int i=tid; i<8*64; i+=256){
    int r=i>>6, d=i&63; int l=l0+r;
    qs[r][d] = (l<198) ? qkv[((size_t)(l*32+bb))*2304 + h*64 + d] : 0.f;
  }
  __syncthreads();
  int nr = min(8, 198-l0);
  for (int r=0; r<nr; ++r){
    float s = -1e30f;
    if (tid < 198){
      float a=0.f;
      #pragma unroll
      for (int d=0;d<64;++d) a += qs[r][d]*Ks[tid*65+d];
      s = a*0.125f;
      ps[r][tid] = s;
    }
    __syncthreads();
    if (tid < 64){
      float m=-1e30f;
      for (int j=tid; j<198; j+=64) m = fmaxf(m, ps[r][j]);
      m = wave_max(m);
      if (tid==0) red[0]=m;
    }
    __syncthreads();
    float mx = red[0];
    float ev = 0.f;
    if (tid<198){ ev = expf(s-mx); ps[r][tid]=ev; }
    __syncthreads();
    if (tid < 64){
      float t2=0.f;
      for (int j=tid; j<198; j+=64) t2 += ps[r][j];
      t2 = wave_sum(t2);
      if (tid==0) red[1]=t2;
    }
    __syncthreads();
    float inv = 1.f/red[1];
    if (tid<198) ps[r][tid] = ev*inv;
    __syncthreads();
  }
  // V phase
  for (int i=tid; i<198*64; i+=256){
    int m=i>>6, d=i&63;
    Ks[m*65+d] = qkv[((size_t)(m*32+bb))*2304 + 1536 + h*64 + d];
  }
  __syncthreads();
  for (int o=tid; o<nr*64; o+=256){
    int r=o>>6, d=o&63;
    float a=0.f;
    for (int m=0;m<198;++m) a += ps[r][m]*Ks[m*65+d];
    attno[((size_t)((l0+r)*32+bb))*768 + h*64 + d] = a;
  }
}

// ---------------- generic tiled GEMM: C[M,N] = res + A[M,K] @ B[N,K]^T + bias ----------------
__global__ __launch_bounds__(256) void gemm_nt(const float* __restrict__ A,
    const float* __restrict__ B, const float* __restrict__ bias,
    const float* res, float* C,
    int M, int N, int K){
  __shared__ __align__(16) float As[16][68];
  __shared__ __align__(16) float Bs[16][68];
  int tid=threadIdx.x, tx=tid&15, ty=tid>>4;
  int row0=blockIdx.y*64, col0=blockIdx.x*64;
  int lrow=tid>>2, lk4=(tid&3)*4;
  float acc[4][4]={};
  for (int kb=0; kb<K; kb+=16){
    int gr = row0 + lrow;
    if (gr < M){
      float a0,a1,a2,a3; ld4(A + (size_t)gr*K + kb + lk4, a0,a1,a2,a3);
      As[lk4][lrow]=a0; As[lk4+1][lrow]=a1; As[lk4+2][lrow]=a2; As[lk4+3][lrow]=a3;
    } else {
      As[lk4][lrow]=0.f; As[lk4+1][lrow]=0.f; As[lk4+2][lrow]=0.f; As[lk4+3][lrow]=0.f;
    }
    { float c0,c1,c2,c3; ld4(B + (size_t)(col0+lrow)*K + kb + lk4, c0,c1,c2,c3);
      Bs[lk4][lrow]=c0; Bs[lk4+1][lrow]=c1; Bs[lk4+2][lrow]=c2; Bs[lk4+3][lrow]=c3; }
    __syncthreads();
    #pragma unroll
    for (int kk=0;kk<16;++kk){
      float4 a4 = *reinterpret_cast<const float4*>(&As[kk][ty*4]);
      float4 b4 = *reinterpret_cast<const float4*>(&Bs[kk][tx*4]);
      float av[4]={a4.x,a4.y,a4.z,a4.w};
      float bw[4]={b4.x,b4.y,b4.z,b4.w};
      #pragma unroll
      for (int u=0;u<4;++u)
        #pragma unroll
        for (int v=0;v<4;++v) acc[u][v] += av[u]*bw[v];
    }
    __syncthreads();
  }
  #pragma unroll
  for (int u=0;u<4;++u){
    int gi = row0 + ty*4 + u;
    if (gi >= M) continue;
    #pragma unroll
    for (int v=0;v<4;++v){
      int gj = col0 + tx*4 + v;
      float r = res ? res[(size_t)gi*N+gj] : 0.f;
      float bb = bias ? bias[gj] : 0.f;
      C[(size_t)gi*N+gj] = r + acc[u][v] + bb;
    }
  }
}

// ---------------- fused 5-expert heads GEMM: oh = qgelu( sum_e r1_e (lnx@Wh_e^T + bh_e) ) ----------------
__global__ __launch_bounds__(256) void gemm_moe_heads(const float* __restrict__ A,
    const float* __restrict__ r1,
    const float* __restrict__ cfc_w, const float* __restrict__ cfc_b,
    const float* __restrict__ eh_w, const float* __restrict__ eh_b,
    float* __restrict__ oh){
  const int M=6304, N=3072, K=768;
  __shared__ __align__(16) float As[16][68];
  __shared__ __align__(16) float Bs[16][68];
  __shared__ float r1s[64][5];
  int tid=threadIdx.x, tx=tid&15, ty=tid>>4;
  int row0=blockIdx.y*64, col0=blockIdx.x*64;
  for (int i=tid; i<320; i+=256){
    int rr=i/5, ee=i%5; int gi=row0+rr;
    r1s[rr][ee] = (gi<M) ? r1[(size_t)gi*5+ee] : 0.f;
  }
  int lrow=tid>>2, lk4=(tid&3)*4;
  float tot[4][4]={};
  for (int e=0;e<5;++e){
    const float* Bp = e ? eh_w + (size_t)(e-1)*N*K : cfc_w;
    const float* bp = e ? eh_b + (size_t)(e-1)*N   : cfc_b;
    float acc[4][4]={};
    for (int kb=0; kb<K; kb+=16){
      int gr = row0 + lrow;
      if (gr < M){
        float a0,a1,a2,a3; ld4(A + (size_t)gr*K + kb + lk4, a0,a1,a2,a3);
        As[lk4][lrow]=a0; As[lk4+1][lrow]=a1; As[lk4+2][lrow]=a2; As[lk4+3][lrow]=a3;
      } else {
        As[lk4][lrow]=0.f; As[lk4+1][lrow]=0.f; As[lk4+2][lrow]=0.f; As[lk4+3][lrow]=0.f;
      }
      { float c0,c1,c2,c3; ld4(Bp + (size_t)(col0+lrow)*K + kb + lk4, c0,c1,c2,c3);
        Bs[lk4][lrow]=c0; Bs[lk4+1][lrow]=c1; Bs[lk4+2][lrow]=c2; Bs[lk4+3][lrow]=c3; }
      __syncthreads();
      #pragma unroll
      for (int kk=0;kk<16;++kk){
        float4 a4 = *reinterpret_cast<const float4*>(&As[kk][ty*4]);
        float4 b4 = *reinterpret_cast<const float4*>(&Bs[kk][tx*4]);
        float av[4]={a4.x,a4.y,a4.z,a4.w};
        float bw[4]={b4.x,b4.y,b4.z,b4.w};
        #pragma unroll
        for (int u=0;u<4;++u)
          #pragma unroll
          for (int v=0;v<4;++v) acc[u][v] += av[u]*bw[v];
      }
      __syncthreads();
    }
    float bb[4];
    #pragma unroll
    for (int v=0;v<4;++v) bb[v] = bp[col0 + tx*4 + v];
    #pragma unroll
    for (int u=0;u<4;++u){
      float w = r1s[ty*4+u][e];
      #pragma unroll
      for (int v=0;v<4;++v) tot[u][v] += w*(acc[u][v] + bb[v]);
    }
  }
  #pragma unroll
  for (int u=0;u<4;++u){
    int gi = row0 + ty*4 + u;
    if (gi >= M) continue;
    #pragma unroll
    for (int v=0;v<4;++v){
      int gj = col0 + tx*4 + v;
      float x = tot[u][v];
      oh[(size_t)gi*N+gj] = x / (1.f + expf(-1.702f*x));  // qgelu
    }
  }
}

// ---------------- fused 5-expert tails GEMM: out = xc + sum_e r2_e (oh@Wt_e^T + bt_e) ----------------
__global__ __launch_bounds__(256) void gemm_moe_tails(const float* __restrict__ A,
    const float* __restrict__ r2,
    const float* __restrict__ cproj_w, const float* __restrict__ cproj_b,
    const float* __restrict__ et_w, const float* __restrict__ et_b,
    const float* __restrict__ xres, float* __restrict__ outp){
  const int M=6304, N=768, K=3072;
  __shared__ __align__(16) float As[16][68];
  __shared__ __align__(16) float Bs[16][68];
  __shared__ float r2s[64][5];
  int tid=threadIdx.x, tx=tid&15, ty=tid>>4;
  int row0=blockIdx.y*64, col0=blockIdx.x*64;
  for (int i=tid; i<320; i+=256){
    int rr=i/5, ee=i%5; int gi=row0+rr;
    r2s[rr][ee] = (gi<M) ? r2[(size_t)gi*5+ee] : 0.f;
  }
  int lrow=tid>>2, lk4=(tid&3)*4;
  float tot[4][4]={};
  for (int e=0;e<5;++e){
    const float* Bp = e ? et_w + (size_t)(e-1)*N*K : cproj_w;
    const float* bp = e ? et_b + (size_t)(e-1)*N   : cproj_b;
    float acc[4][4]={};
    for (int kb=0; kb<K; kb+=16){
      int gr = row0 + lrow;
      if (gr < M){
        float a0,a1,a2,a3; ld4(A + (size_t)gr*K + kb + lk4, a0,a1,a2,a3);
        As[lk4][lrow]=a0; As[lk4+1][lrow]=a1; As[lk4+2][lrow]=a2; As[lk4+3][lrow]=a3;
      } else {
        As[lk4][lrow]=0.f; As[lk4+1][lrow]=0.f; As[lk4+2][lrow]=0.f; As[lk4+3][lrow]=0.f;
      }
      { float c0,c1,c2,c3; ld4(Bp + (size_t)(col0+lrow)*K + kb + lk4, c0,c1,c2,c3);
        Bs[lk4][lrow]=c0; Bs[lk4+1][lrow]=c1; Bs[lk4+2][lrow]=c2; Bs[lk4+3][lrow]=c3; }
      __syncthreads();
      #pragma unroll
      for (int kk=0;kk<16;++kk){
        float4 a4 = *reinterpret_cast<const float4*>(&As[kk][ty*4]);
        float4 b4 = *reinterpret_cast<const float4*>(&Bs[kk][tx*4]);
        float av[4]={a4.x,a4.y,a4.z,a4.w};
        float bw[4]={b4.x,b4.y,b4.z,b4.w};
        #pragma unroll
        for (int u=0;u<4;++u)
          #pragma unroll
          for (int v=0;v<4;++v) acc[u][v] += av[u]*bw[v];
      }
      __syncthreads();
    }
    float bb[4];
    #pragma unroll
    for (int v=0;v<4;++v) bb[v] = bp[col0 + tx*4 + v];
    #pragma unroll
    for (int u=0;u<4;++u){
      float w = r2s[ty*4+u][e];
      #pragma unroll
      for (int v=0;v<4;++v) tot[u][v] += w*(acc[u][v] + bb[v]);
    }
  }
  #pragma unroll
  for (int u=0;u<4;++u){
    int gi = row0 + ty*4 + u;
    if (gi >= M) continue;
    #pragma unroll
    for (int v=0;v<4;++v){
      int gj = col0 + tx*4 + v;
      outp[(size_t)gi*N+gj] = xres[(size_t)gi*N+gj] + tot[u][v];
    }
  }
}

extern "C" void kernel_launch(void* const* d_in, const int* in_sizes, int n_in,
                              void* d_out, int out_size, void* d_ws, size_t ws_size,
                              hipStream_t stream) {
  const float* x         = (const float*)d_in[0];
  const float* msg_fc_w  = (const float*)d_in[1];
  const float* msg_fc_b  = (const float*)d_in[2];
  const float* msg_ln_g  = (const float*)d_in[3];
  const float* msg_ln_b  = (const float*)d_in[4];
  const float* msg_wqkv  = (const float*)d_in[5];
  const float* msg_bqkv  = (const float*)d_in[6];
  const float* msg_wo    = (const float*)d_in[7];
  const float* msg_bo    = (const float*)d_in[8];
  const float* attn_wqkv = (const float*)d_in[9];
  const float* attn_bqkv = (const float*)d_in[10];
  const float* attn_wo   = (const float*)d_in[11];
  const float* attn_bo   = (const float*)d_in[12];
  const float* ln1_g     = (const float*)d_in[13];
  const float* ln1_b     = (const float*)d_in[14];
  const float* ln2_g     = (const float*)d_in[15];
  const float* ln2_b     = (const float*)d_in[16];
  const float* cfc_w     = (const float*)d_in[17];
  const float* cfc_b     = (const float*)d_in[18];
  const float* cproj_w   = (const float*)d_in[19];
  const float* cproj_b   = (const float*)d_in[20];
  const float* eh_w      = (const float*)d_in[21];
  const float* eh_b      = (const float*)d_in[22];
  const float* et_w      = (const float*)d_in[23];
  const float* et_b      = (const float*)d_in[24];
  const float* r1_w      = (const float*)d_in[25];
  const float* r1_b      = (const float*)d_in[26];
  const float* r2_w      = (const float*)d_in[27];
  const float* r2_b      = (const float*)d_in[28];
  float* out = (float*)d_out;

  // workspace layout (floats)
  float* ws    = (float*)d_ws;
  float* xc    = ws;                       // 198*32*768 = 4,866,048
  float* lnb   = xc    + 4866048;          // 4,866,048 (ln1 out -> attno -> ln_x)
  float* big   = lnb   + 4866048;          // 19,365,888 (qkv 6336x2304, then oh 6304x3072)
  float* r1b   = big   + 19365888;         // 31,520
  float* r2b   = r1b   + 31520;            // 31,520
  float* msg   = r2b   + 31520;            // 24,576
  float* mln   = msg   + 24576;            // 24,576
  float* mqkv  = mln   + 24576;            // 73,728
  float* matt  = mqkv  + 73728;            // 24,576

  // 1. xc[0:6304] = x (d2d copy)
  hipMemcpyAsync(xc, x, (size_t)4841472*sizeof(float), hipMemcpyDeviceToDevice, stream);
  // 2. msg0 = x[0] @ msg_fc_w^T + b  (rows are (b,t))
  gemm_nt<<<dim3(12,1), dim3(256), 0, stream>>>(x, msg_fc_w, msg_fc_b, nullptr, msg, 32, 768, 768);
  // 3. mln = LN(msg0)
  ln_rows<<<dim3(32), dim3(256), 0, stream>>>(msg, msg_ln_g, msg_ln_b, mln);
  // 4. mqkv = mln @ wqkv^T + bqkv
  gemm_nt<<<dim3(36,1), dim3(256), 0, stream>>>(mln, msg_wqkv, msg_bqkv, nullptr, mqkv, 32, 2304, 768);
  // 5. msg self-attention (seq=8 per b)
  msg_attn<<<dim3(48), dim3(64), 0, stream>>>(mqkv, matt);
  // 6. xc row block 197 = msg0 + matt @ wo^T + bo
  gemm_nt<<<dim3(12,1), dim3(256), 0, stream>>>(matt, msg_wo, msg_bo, msg, xc + (size_t)6304*768, 32, 768, 768);
  // 7. ln1 over all 6336 rows
  ln_rows<<<dim3(6336), dim3(256), 0, stream>>>(xc, ln1_g, ln1_b, lnb);
  // 8. qkv = ln1 @ attn_wqkv^T + bqkv
  gemm_nt<<<dim3(36,99), dim3(256), 0, stream>>>(lnb, attn_wqkv, attn_bqkv, nullptr, big, 6336, 2304, 768);
  // 9. attention (198 keys), attno -> lnb
  attn198<<<dim3(384,25), dim3(256), 0, stream>>>(big, lnb);
  // 10. xc += attno @ wo^T + bo
  gemm_nt<<<dim3(12,99), dim3(256), 0, stream>>>(lnb, attn_wo, attn_bo, xc, xc, 6336, 768, 768);
  // 11. ln_x = LN(xc[:6304]) -> lnb
  ln_rows<<<dim3(6304), dim3(256), 0, stream>>>(xc, ln2_g, ln2_b, lnb);
  // 12. r1 = softmax(ln_x @ r1_w^T + r1_b)
  router<<<dim3(6304), dim3(64), 0, stream>>>(lnb, r1_w, r1_b, r1b, 768);
  // 13. oh = qgelu(sum_e r1_e (ln_x @ Wh_e^T + bh_e)) -> big
  gemm_moe_heads<<<dim3(48,99), dim3(256), 0, stream>>>(lnb, r1b, cfc_w, cfc_b, eh_w, eh_b, big);
  // 14. r2 = softmax(oh @ r2_w^T + r2_b)
  router<<<dim3(6304), dim3(64), 0, stream>>>(big, r2_w, r2_b, r2b, 3072);
  // 15. out = xc + sum_e r2_e (oh @ Wt_e^T + bt_e)
  gemm_moe_tails<<<dim3(12,99), dim3(256), 0, stream>>>(big, r2b, cproj_w, cproj_b, et_w, et_b, xc, out);
}

// Round 3
// 1829.168 us; speedup vs baseline: 3.1792x; 3.1792x over previous
//
#include <hip/hip_runtime.h>
#include <hip/hip_bf16.h>

typedef __hip_bfloat16 bf16;
typedef __attribute__((ext_vector_type(8))) short short8;      // 8 bf16 in 4 VGPRs (guide §3)
typedef __attribute__((ext_vector_type(4))) float f32x4;

__device__ __forceinline__ float b2f(bf16 v){ return __bfloat162float(v); }

__device__ __forceinline__ void gload16(const bf16* g, bf16* l){
  // async global->LDS, 16B per lane; LDS dest = wave-uniform base + lane*16
  __builtin_amdgcn_global_load_lds((const __attribute__((address_space(1))) void*)g,
                                   (__attribute__((address_space(3))) void*)l, 16, 0, 0);
}

__device__ __forceinline__ void ld4(const float* p, float& a,float& b,float& c,float& d){
  float4 v = *reinterpret_cast<const float4*>(p); a=v.x; b=v.y; c=v.z; d=v.w;
}
__device__ __forceinline__ float wave_sum(float v){
  #pragma unroll
  for (int off=32; off>0; off>>=1) v += __shfl_down(v, off);
  return v;
}
__device__ __forceinline__ float wave_max(float v){
  #pragma unroll
  for (int off=32; off>0; off>>=1) v = fmaxf(v, __shfl_down(v, off));
  return v;
}

// ---------------- fp32 -> bf16 convert ----------------
__global__ __launch_bounds__(256) void cvt_f2b(const float* __restrict__ in, bf16* __restrict__ out, int n){
  int i = (blockIdx.x*256 + threadIdx.x)*4;
  if (i+3 < n){
    float4 v = *reinterpret_cast<const float4*>(in+i);
    out[i]   = __float2bfloat16(v.x);
    out[i+1] = __float2bfloat16(v.y);
    out[i+2] = __float2bfloat16(v.z);
    out[i+3] = __float2bfloat16(v.w);
  } else {
    for (int j=i; j<n; ++j) out[j] = __float2bfloat16(in[j]);
  }
}

// ---------------- row LayerNorm: fp32 in, fp32 out ----------------
__global__ __launch_bounds__(256) void ln_rows(const float* __restrict__ in,
    const float* __restrict__ g, const float* __restrict__ b,
    float* __restrict__ out){
  int row = blockIdx.x;
  const float* x = in + (size_t)row*768;
  float* o = out + (size_t)row*768;
  float s=0.f, s2=0.f;
  for (int d=threadIdx.x; d<768; d+=256){ float v=x[d]; s+=v; s2+=v*v; }
  s = wave_sum(s); s2 = wave_sum(s2);
  __shared__ float red[8];
  __shared__ float stat[2];
  int lane = threadIdx.x & 63, wid = threadIdx.x >> 6;
  if (lane==0){ red[wid]=s; red[4+wid]=s2; }
  __syncthreads();
  if (threadIdx.x==0){
    float S=red[0]+red[1]+red[2]+red[3];
    float S2=red[4]+red[5]+red[6]+red[7];
    float m = S*(1.f/768.f);
    float var = S2*(1.f/768.f) - m*m;
    stat[0]=m; stat[1]=rsqrtf(var + 1e-5f);
  }
  __syncthreads();
  float m=stat[0], inv=stat[1];
  for (int d=threadIdx.x; d<768; d+=256)
    o[d] = (x[d]-m)*inv*g[d] + b[d];
}

// ---------------- row LayerNorm: fp32 in, bf16 out ----------------
__global__ __launch_bounds__(256) void ln_rows_b(const float* __restrict__ in,
    const float* __restrict__ g, const float* __restrict__ b,
    bf16* __restrict__ out){
  int row = blockIdx.x;
  const float* x = in + (size_t)row*768;
  bf16* o = out + (size_t)row*768;
  float s=0.f, s2=0.f;
  for (int d=threadIdx.x; d<768; d+=256){ float v=x[d]; s+=v; s2+=v*v; }
  s = wave_sum(s); s2 = wave_sum(s2);
  __shared__ float red[8];
  __shared__ float stat[2];
  int lane = threadIdx.x & 63, wid = threadIdx.x >> 6;
  if (lane==0){ red[wid]=s; red[4+wid]=s2; }
  __syncthreads();
  if (threadIdx.x==0){
    float S=red[0]+red[1]+red[2]+red[3];
    float S2=red[4]+red[5]+red[6]+red[7];
    float m = S*(1.f/768.f);
    float var = S2*(1.f/768.f) - m*m;
    stat[0]=m; stat[1]=rsqrtf(var + 1e-5f);
  }
  __syncthreads();
  float m=stat[0], inv=stat[1];
  for (int d=threadIdx.x; d<768; d+=256)
    o[d] = __float2bfloat16((x[d]-m)*inv*g[d] + b[d]);
}

// ---------------- router: softmax( Xbf16 @ Wfp32^T + b ) over 5 experts ----------------
__global__ __launch_bounds__(64) void router(const bf16* __restrict__ X,
    const float* __restrict__ W, const float* __restrict__ bias,
    float* __restrict__ out, int K){
  int row = blockIdx.x, lane = threadIdx.x;
  const bf16* x = X + (size_t)row*K;
  float lg[5];
  #pragma unroll
  for (int e=0;e<5;++e){
    const float* w = W + (size_t)e*K;
    float p=0.f;
    for (int d=lane; d<K; d+=64) p += b2f(x[d])*w[d];
    lg[e] = wave_sum(p);
  }
  if (lane==0){
    float mx=-1e30f;
    #pragma unroll
    for (int e=0;e<5;++e){ lg[e] += bias[e]; mx = fmaxf(mx, lg[e]); }
    float s=0.f;
    #pragma unroll
    for (int e=0;e<5;++e){ lg[e]=expf(lg[e]-mx); s+=lg[e]; }
    float inv=1.f/s;
    #pragma unroll
    for (int e=0;e<5;++e) out[(size_t)row*5+e] = lg[e]*inv;
  }
}

// ---------------- msg attention: seq=8 within each b, 12 heads (fp32) ----------------
__global__ __launch_bounds__(64) void msg_attn(const float* __restrict__ mqkv,
    float* __restrict__ mattno){
  int bh = blockIdx.x; int b = bh/12, h = bh%12;
  __shared__ float qs[8][64], ks[8][64], vs[8][64], sc[8][8];
  int lane = threadIdx.x;
  for (int i=lane; i<512; i+=64){
    int t=i>>6, d=i&63;
    size_t base = ((size_t)(b*8+t))*2304 + h*64 + d;
    qs[t][d]=mqkv[base]; ks[t][d]=mqkv[base+768]; vs[t][d]=mqkv[base+1536];
  }
  __syncthreads();
  { int t=lane>>3, m=lane&7; float a=0.f;
    #pragma unroll
    for (int d=0;d<64;++d) a += qs[t][d]*ks[m][d];
    sc[t][m] = a*0.125f; }
  __syncthreads();
  if (lane<8){
    int t=lane; float mx=-1e30f;
    #pragma unroll
    for (int m=0;m<8;++m) mx=fmaxf(mx, sc[t][m]);
    float s=0.f;
    #pragma unroll
    for (int m=0;m<8;++m){ float e=expf(sc[t][m]-mx); sc[t][m]=e; s+=e; }
    float inv=1.f/s;
    #pragma unroll
    for (int m=0;m<8;++m) sc[t][m]*=inv;
  }
  __syncthreads();
  { int t=lane>>3, d0=(lane&7)*8;
    for (int dd=0; dd<8; ++dd){
      int d=d0+dd; float a=0.f;
      #pragma unroll
      for (int m=0;m<8;++m) a += sc[t][m]*vs[m][d];
      mattno[((size_t)(b*8+t))*768 + h*64 + d] = a;
    } }
}

// ---------------- main attention: seq=198, batch=32, 12 heads; bf16 qkv in, bf16 out ----------------
__global__ __launch_bounds__(256) void attn198(const bf16* __restrict__ qkv,
    bf16* __restrict__ attno){
  int bh = blockIdx.x; int bb = bh/12, h = bh%12;
  int l0 = blockIdx.y*8;
  __shared__ float Ks[198*65];
  __shared__ float qs[8][64];
  __shared__ float ps[8][200];
  __shared__ float red[2];
  int tid = threadIdx.x;
  for (int i=tid; i<198*64; i+=256){
    int m=i>>6, d=i&63;
    Ks[m*65+d] = b2f(qkv[((size_t)(m*32+bb))*2304 + 768 + h*64 + d]);
  }
  for (int i=tid; i<8*64; i+=256){
    int r=i>>6, d=i&63; int l=l0+r;
    qs[r][d] = (l<198) ? b2f(qkv[((size_t)(l*32+bb))*2304 + h*64 + d]) : 0.f;
  }
  __syncthreads();
  int nr = min(8, 198-l0);
  for (int r=0; r<nr; ++r){
    float s = -1e30f;
    if (tid < 198){
      float a=0.f;
      #pragma unroll
      for (int d=0;d<64;++d) a += qs[r][d]*Ks[tid*65+d];
      s = a*0.125f;
      ps[r][tid] = s;
    }
    __syncthreads();
    if (tid < 64){
      float m=-1e30f;
      for (int j=tid; j<198; j+=64) m = fmaxf(m, ps[r][j]);
      m = wave_max(m);
      if (tid==0) red[0]=m;
    }
    __syncthreads();
    float mx = red[0];
    float ev = 0.f;
    if (tid<198){ ev = expf(s-mx); ps[r][tid]=ev; }
    __syncthreads();
    if (tid < 64){
      float t2=0.f;
      for (int j=tid; j<198; j+=64) t2 += ps[r][j];
      t2 = wave_sum(t2);
      if (tid==0) red[1]=t2;
    }
    __syncthreads();
    float inv = 1.f/red[1];
    if (tid<198) ps[r][tid] = ev*inv;
    __syncthreads();
  }
  // V phase
  for (int i=tid; i<198*64; i+=256){
    int m=i>>6, d=i&63;
    Ks[m*65+d] = b2f(qkv[((size_t)(m*32+bb))*2304 + 1536 + h*64 + d]);
  }
  __syncthreads();
  for (int o=tid; o<nr*64; o+=256){
    int r=o>>6, d=o&63;
    float a=0.f;
    for (int m=0;m<198;++m) a += ps[r][m]*Ks[m*65+d];
    attno[((size_t)((l0+r)*32+bb))*768 + h*64 + d] = __float2bfloat16(a);
  }
}

// ---------------- small fp32 tiled GEMM for msg branch ----------------
__global__ __launch_bounds__(256) void gemm_nt(const float* __restrict__ A,
    const float* __restrict__ B, const float* __restrict__ bias,
    const float* res, float* C,
    int M, int N, int K){
  __shared__ __align__(16) float As[16][68];
  __shared__ __align__(16) float Bs[16][68];
  int tid=threadIdx.x, tx=tid&15, ty=tid>>4;
  int row0=blockIdx.y*64, col0=blockIdx.x*64;
  int lrow=tid>>2, lk4=(tid&3)*4;
  float acc[4][4]={};
  for (int kb=0; kb<K; kb+=16){
    int gr = row0 + lrow;
    if (gr < M){
      float a0,a1,a2,a3; ld4(A + (size_t)gr*K + kb + lk4, a0,a1,a2,a3);
      As[lk4][lrow]=a0; As[lk4+1][lrow]=a1; As[lk4+2][lrow]=a2; As[lk4+3][lrow]=a3;
    } else {
      As[lk4][lrow]=0.f; As[lk4+1][lrow]=0.f; As[lk4+2][lrow]=0.f; As[lk4+3][lrow]=0.f;
    }
    { float c0,c1,c2,c3; ld4(B + (size_t)(col0+lrow)*K + kb + lk4, c0,c1,c2,c3);
      Bs[lk4][lrow]=c0; Bs[lk4+1][lrow]=c1; Bs[lk4+2][lrow]=c2; Bs[lk4+3][lrow]=c3; }
    __syncthreads();
    #pragma unroll
    for (int kk=0;kk<16;++kk){
      float4 a4 = *reinterpret_cast<const float4*>(&As[kk][ty*4]);
      float4 b4 = *reinterpret_cast<const float4*>(&Bs[kk][tx*4]);
      float av[4]={a4.x,a4.y,a4.z,a4.w};
      float bw[4]={b4.x,b4.y,b4.z,b4.w};
      #pragma unroll
      for (int u=0;u<4;++u)
        #pragma unroll
        for (int v=0;v<4;++v) acc[u][v] += av[u]*bw[v];
    }
    __syncthreads();
  }
  #pragma unroll
  for (int u=0;u<4;++u){
    int gi = row0 + ty*4 + u;
    if (gi >= M) continue;
    #pragma unroll
    for (int v=0;v<4;++v){
      int gj = col0 + tx*4 + v;
      float r = res ? res[(size_t)gi*N+gj] : 0.f;
      float bb = bias ? bias[gj] : 0.f;
      C[(size_t)gi*N+gj] = r + acc[u][v] + bb;
    }
  }
}

// ================= MFMA bf16 GEMM, 128x128 tile, BK=32 (m97 recipe) =================
// C[M,N] = A[M,K] @ B[(e,)N,K]^T  with per-mode epilogue.
// MODE 0 (QKV):   + bias            -> bf16 out
// MODE 1 (WO):    + bias + res      -> f32 out
// MODE 2 (HEADS): sum_e r_e(acc+bias_e), qgelu -> bf16 out
// MODE 3 (TAILS): sum_e r_e(acc+bias_e) + res -> f32 out
template<int MODE>
__global__ __launch_bounds__(256,2) void gemm_mfma(
    const bf16* __restrict__ A, const bf16* __restrict__ B,
    const float* __restrict__ bias, const float* __restrict__ rmat,
    const float* __restrict__ res, float* __restrict__ outf,
    bf16* __restrict__ outb, int M, int N, int K)
{
  constexpr int NE = (MODE>=2) ? 5 : 1;
  __shared__ __align__(16) bf16 As[128*32];
  __shared__ __align__(16) bf16 Bs[128*32];
  __shared__ float rls[(MODE>=2) ? 640 : 4];

  int tid=threadIdx.x, wv=tid>>6, ln=tid&63;
  int quad=ln>>4, mrow=ln&15;
  int row0=blockIdx.y*128, col0=blockIdx.x*128;
  int wr=wv>>1, wc=wv&1;

  if (MODE>=2){
    for (int i=tid; i<640; i+=256) rls[i] = rmat[(size_t)row0*5 + i];
  }

  // staging: 512 chunks of 16B per matrix; this thread handles chunk c0 and c0+256
  int c0 = wv*64 + ln;
  int r0 = c0>>2, cc=(c0&3)*8;
  bf16* lA0 = As + wv*512;         // + implicit lane*16B
  bf16* lA1 = As + 2048 + wv*512;
  bf16* lB0 = Bs + wv*512;
  bf16* lB1 = Bs + 2048 + wv*512;

  int aoff[4], boff[4];
  #pragma unroll
  for (int i=0;i<4;++i){
    aoff[i] = (wr*64 + i*16 + mrow)*32 + quad*8;
    boff[i] = (wc*64 + i*16 + mrow)*32 + quad*8;
  }

  float tot[4][4][4];
  if (MODE>=2){
    #pragma unroll
    for (int i=0;i<4;++i)
      #pragma unroll
      for (int j=0;j<4;++j)
        #pragma unroll
        for (int r=0;r<4;++r) tot[i][j][r]=0.f;
  }
  f32x4 acc[4][4];
  const f32x4 zero = {0.f,0.f,0.f,0.f};

  for (int e=0;e<NE;++e){
    const bf16* Be = B + (size_t)e*N*K;
    #pragma unroll
    for (int i=0;i<4;++i)
      #pragma unroll
      for (int j=0;j<4;++j) acc[i][j]=zero;

    const bf16* Ab = A + (size_t)(row0+r0)*K + cc;
    const bf16* Bb = Be + (size_t)(col0+r0)*K + cc;
    for (int kb=0; kb<K; kb+=32){
      gload16(Ab + kb, lA0);
      gload16(Ab + (size_t)64*K + kb, lA1);
      gload16(Bb + kb, lB0);
      gload16(Bb + (size_t)64*K + kb, lB1);
      __syncthreads();
      short8 af[4], bfr[4];
      #pragma unroll
      for (int i=0;i<4;++i) af[i]  = *reinterpret_cast<const short8*>(As + aoff[i]);
      #pragma unroll
      for (int j=0;j<4;++j) bfr[j] = *reinterpret_cast<const short8*>(Bs + boff[j]);
      #pragma unroll
      for (int i=0;i<4;++i)
        #pragma unroll
        for (int j=0;j<4;++j)
          acc[i][j] = __builtin_amdgcn_mfma_f32_16x16x32_bf16(af[i], bfr[j], acc[i][j], 0, 0, 0);
      __syncthreads();
    }
    if (MODE>=2){
      #pragma unroll
      for (int i=0;i<4;++i){
        #pragma unroll
        for (int r=0;r<4;++r){
          int lr = wr*64 + i*16 + quad*4 + r;
          float w = rls[lr*5+e];
          #pragma unroll
          for (int j=0;j<4;++j){
            int gc = col0 + wc*64 + j*16 + mrow;
            tot[i][j][r] += w*(acc[i][j][r] + bias[e*N + gc]);
          }
        }
      }
    }
  }

  // epilogue
  #pragma unroll
  for (int i=0;i<4;++i){
    #pragma unroll
    for (int r=0;r<4;++r){
      int gi = row0 + wr*64 + i*16 + quad*4 + r;
      if (gi >= M) continue;
      #pragma unroll
      for (int j=0;j<4;++j){
        int gj = col0 + wc*64 + j*16 + mrow;
        float v;
        if (MODE==0)      v = acc[i][j][r] + bias[gj];
        else if (MODE==1) v = acc[i][j][r] + bias[gj] + res[(size_t)gi*N+gj];
        else if (MODE==2){ float x = tot[i][j][r]; v = x/(1.f+expf(-1.702f*x)); }
        else              v = tot[i][j][r] + res[(size_t)gi*N+gj];
        if (MODE==0 || MODE==2) outb[(size_t)gi*N+gj] = __float2bfloat16(v);
        else                    outf[(size_t)gi*N+gj] = v;
      }
    }
  }
}

extern "C" void kernel_launch(void* const* d_in, const int* in_sizes, int n_in,
                              void* d_out, int out_size, void* d_ws, size_t ws_size,
                              hipStream_t stream) {
  const float* x         = (const float*)d_in[0];
  const float* msg_fc_w  = (const float*)d_in[1];
  const float* msg_fc_b  = (const float*)d_in[2];
  const float* msg_ln_g  = (const float*)d_in[3];
  const float* msg_ln_b  = (const float*)d_in[4];
  const float* msg_wqkv  = (const float*)d_in[5];
  const float* msg_bqkv  = (const float*)d_in[6];
  const float* msg_wo    = (const float*)d_in[7];
  const float* msg_bo    = (const float*)d_in[8];
  const float* attn_wqkv = (const float*)d_in[9];
  const float* attn_bqkv = (const float*)d_in[10];
  const float* attn_wo   = (const float*)d_in[11];
  const float* attn_bo   = (const float*)d_in[12];
  const float* ln1_g     = (const float*)d_in[13];
  const float* ln1_b     = (const float*)d_in[14];
  const float* ln2_g     = (const float*)d_in[15];
  const float* ln2_b     = (const float*)d_in[16];
  const float* cfc_w     = (const float*)d_in[17];
  const float* cfc_b     = (const float*)d_in[18];
  const float* cproj_w   = (const float*)d_in[19];
  const float* cproj_b   = (const float*)d_in[20];
  const float* eh_w      = (const float*)d_in[21];
  const float* eh_b      = (const float*)d_in[22];
  const float* et_w      = (const float*)d_in[23];
  const float* et_b      = (const float*)d_in[24];
  const float* r1_w      = (const float*)d_in[25];
  const float* r1_b      = (const float*)d_in[26];
  const float* r2_w      = (const float*)d_in[27];
  const float* r2_b      = (const float*)d_in[28];
  float* out = (float*)d_out;

  // ---- workspace layout (float units) ----
  float* ws     = (float*)d_ws;
  float* xc     = ws;                        // 6336*768 f32            = 4,866,048
  float* bigA   = xc + 4866048;              // region: 9,830,400 f
  bf16*  qkv_b  = (bf16*)bigA;               //   qkv: 6400*2304 bf16
  bf16*  oh_b   = (bf16*)bigA;               //   oh : 6400*3072 bf16 (reuse after attn)
  float* lnbf   = bigA + 9830400;            // 6400*768 bf16 region    = 2,457,600 f
  bf16*  lnb_b  = (bf16*)lnbf;
  float* attnof = lnbf + 2457600;            // 6400*768 bf16 region    = 2,457,600 f
  bf16*  attno_b= (bf16*)attnof;
  float* wqf    = attnof + 2457600;          // 2304*768 bf16           = 884,736 f
  bf16*  wq_b   = (bf16*)wqf;
  float* wof    = wqf + 884736;              // 768*768 bf16            = 294,912 f
  bf16*  wo_b   = (bf16*)wof;
  float* whf    = wof + 294912;              // 5*3072*768 bf16         = 5,898,240 f
  bf16*  wh_b   = (bf16*)whf;
  float* wtf    = whf + 5898240;             // 5*768*3072 bf16         = 5,898,240 f
  bf16*  wt_b   = (bf16*)wtf;
  float* bias_h = wtf + 5898240;             // 5*3072
  float* bias_t = bias_h + 15360;            // 5*768
  float* r1b    = bias_t + 3840;             // 6400*5
  float* r2b    = r1b + 32000;               // 6400*5
  float* msg    = r2b + 32000;               // 32*768
  float* mln    = msg + 24576;               // 32*768
  float* mqkv   = mln + 24576;               // 32*2304
  float* matt   = mqkv + 73728;              // 32*768

  // ---- weight conversions fp32 -> bf16 (and bias concat) ----
  cvt_f2b<<<dim3(1769472/4/256), 256, 0, stream>>>(attn_wqkv, wq_b, 1769472);
  cvt_f2b<<<dim3(589824/4/256), 256, 0, stream>>>(attn_wo, wo_b, 589824);
  cvt_f2b<<<dim3(2359296/4/256), 256, 0, stream>>>(cfc_w, wh_b, 2359296);
  cvt_f2b<<<dim3(9437184/4/256), 256, 0, stream>>>(eh_w, wh_b + 2359296, 9437184);
  cvt_f2b<<<dim3(2359296/4/256), 256, 0, stream>>>(cproj_w, wt_b, 2359296);
  cvt_f2b<<<dim3(9437184/4/256), 256, 0, stream>>>(et_w, wt_b + 2359296, 9437184);
  hipMemcpyAsync(bias_h,        cfc_b,   3072*sizeof(float), hipMemcpyDeviceToDevice, stream);
  hipMemcpyAsync(bias_h+3072,   eh_b,   12288*sizeof(float), hipMemcpyDeviceToDevice, stream);
  hipMemcpyAsync(bias_t,        cproj_b,  768*sizeof(float), hipMemcpyDeviceToDevice, stream);
  hipMemcpyAsync(bias_t+768,    et_b,    3072*sizeof(float), hipMemcpyDeviceToDevice, stream);

  // 1. xc[0:6304] = x
  hipMemcpyAsync(xc, x, (size_t)4841472*sizeof(float), hipMemcpyDeviceToDevice, stream);
  // 2. msg branch (fp32, tiny)
  gemm_nt<<<dim3(12,1), 256, 0, stream>>>(x, msg_fc_w, msg_fc_b, nullptr, msg, 32, 768, 768);
  ln_rows<<<dim3(32), 256, 0, stream>>>(msg, msg_ln_g, msg_ln_b, mln);
  gemm_nt<<<dim3(36,1), 256, 0, stream>>>(mln, msg_wqkv, msg_bqkv, nullptr, mqkv, 32, 2304, 768);
  msg_attn<<<dim3(48), 64, 0, stream>>>(mqkv, matt);
  gemm_nt<<<dim3(12,1), 256, 0, stream>>>(matt, msg_wo, msg_bo, msg, xc + (size_t)6304*768, 32, 768, 768);
  // 3. ln1 (6336 rows) -> bf16
  ln_rows_b<<<dim3(6336), 256, 0, stream>>>(xc, ln1_g, ln1_b, lnb_b);
  // 4. qkv = ln1 @ Wqkv^T + b  (MFMA, bf16 out)
  gemm_mfma<0><<<dim3(18,50), 256, 0, stream>>>(lnb_b, wq_b, attn_bqkv, nullptr, nullptr, nullptr, qkv_b, 6336, 2304, 768);
  // 5. attention
  attn198<<<dim3(384,25), 256, 0, stream>>>(qkv_b, attno_b);
  // 6. xc += attno @ Wo^T + bo (MFMA, f32 out)
  gemm_mfma<1><<<dim3(6,50), 256, 0, stream>>>(attno_b, wo_b, attn_bo, nullptr, xc, xc, nullptr, 6336, 768, 768);
  // 7. ln2 (6304 rows) -> bf16
  ln_rows_b<<<dim3(6304), 256, 0, stream>>>(xc, ln2_g, ln2_b, lnb_b);
  // 8. r1 router
  router<<<dim3(6304), 64, 0, stream>>>(lnb_b, r1_w, r1_b, r1b, 768);
  // 9. heads MoE GEMM -> oh (bf16, qgelu)
  gemm_mfma<2><<<dim3(24,50), 256, 0, stream>>>(lnb_b, wh_b, bias_h, r1b, nullptr, nullptr, oh_b, 6304, 3072, 768);
  // 10. r2 router (K=3072)
  router<<<dim3(6304), 64, 0, stream>>>(oh_b, r2_w, r2_b, r2b, 3072);
  // 11. tails MoE GEMM + residual -> out (f32)
  gemm_mfma<3><<<dim3(6,50), 256, 0, stream>>>(oh_b, wt_b, bias_t, r2b, xc, out, nullptr, 6304, 768, 3072);
}

// Round 4
// 1343.095 us; speedup vs baseline: 4.3298x; 1.3619x over previous
//
#include <hip/hip_runtime.h>
#include <hip/hip_bf16.h>

typedef __hip_bfloat16 bf16;
typedef __attribute__((ext_vector_type(8))) short short8;      // 8 bf16 in 4 VGPRs
typedef __attribute__((ext_vector_type(4))) float f32x4;

__device__ __forceinline__ float b2f(bf16 v){ return __bfloat162float(v); }
__device__ __forceinline__ unsigned short f2bits(float v){
  bf16 h = __float2bfloat16(v);
  return *reinterpret_cast<unsigned short*>(&h);
}

__device__ __forceinline__ void gload16(const bf16* g, bf16* l){
  __builtin_amdgcn_global_load_lds((const __attribute__((address_space(1))) void*)g,
                                   (__attribute__((address_space(3))) void*)l, 16, 0, 0);
}

__device__ __forceinline__ void ld4(const float* p, float& a,float& b,float& c,float& d){
  float4 v = *reinterpret_cast<const float4*>(p); a=v.x; b=v.y; c=v.z; d=v.w;
}
__device__ __forceinline__ float wave_sum(float v){
  #pragma unroll
  for (int off=32; off>0; off>>=1) v += __shfl_down(v, off);
  return v;
}

// ---------------- fp32 -> bf16 convert ----------------
__global__ __launch_bounds__(256) void cvt_f2b(const float* __restrict__ in, bf16* __restrict__ out, int n){
  int i = (blockIdx.x*256 + threadIdx.x)*4;
  if (i+3 < n){
    float4 v = *reinterpret_cast<const float4*>(in+i);
    out[i]   = __float2bfloat16(v.x);
    out[i+1] = __float2bfloat16(v.y);
    out[i+2] = __float2bfloat16(v.z);
    out[i+3] = __float2bfloat16(v.w);
  } else {
    for (int j=i; j<n; ++j) out[j] = __float2bfloat16(in[j]);
  }
}

// ---------------- row LayerNorm: fp32 in, fp32 out ----------------
__global__ __launch_bounds__(256) void ln_rows(const float* __restrict__ in,
    const float* __restrict__ g, const float* __restrict__ b,
    float* __restrict__ out){
  int row = blockIdx.x;
  const float* x = in + (size_t)row*768;
  float* o = out + (size_t)row*768;
  float s=0.f, s2=0.f;
  for (int d=threadIdx.x; d<768; d+=256){ float v=x[d]; s+=v; s2+=v*v; }
  s = wave_sum(s); s2 = wave_sum(s2);
  __shared__ float red[8];
  __shared__ float stat[2];
  int lane = threadIdx.x & 63, wid = threadIdx.x >> 6;
  if (lane==0){ red[wid]=s; red[4+wid]=s2; }
  __syncthreads();
  if (threadIdx.x==0){
    float S=red[0]+red[1]+red[2]+red[3];
    float S2=red[4]+red[5]+red[6]+red[7];
    float m = S*(1.f/768.f);
    float var = S2*(1.f/768.f) - m*m;
    stat[0]=m; stat[1]=rsqrtf(var + 1e-5f);
  }
  __syncthreads();
  float m=stat[0], inv=stat[1];
  for (int d=threadIdx.x; d<768; d+=256)
    o[d] = (x[d]-m)*inv*g[d] + b[d];
}

// ---------------- row LayerNorm: fp32 in, bf16 out ----------------
__global__ __launch_bounds__(256) void ln_rows_b(const float* __restrict__ in,
    const float* __restrict__ g, const float* __restrict__ b,
    bf16* __restrict__ out){
  int row = blockIdx.x;
  const float* x = in + (size_t)row*768;
  bf16* o = out + (size_t)row*768;
  float s=0.f, s2=0.f;
  for (int d=threadIdx.x; d<768; d+=256){ float v=x[d]; s+=v; s2+=v*v; }
  s = wave_sum(s); s2 = wave_sum(s2);
  __shared__ float red[8];
  __shared__ float stat[2];
  int lane = threadIdx.x & 63, wid = threadIdx.x >> 6;
  if (lane==0){ red[wid]=s; red[4+wid]=s2; }
  __syncthreads();
  if (threadIdx.x==0){
    float S=red[0]+red[1]+red[2]+red[3];
    float S2=red[4]+red[5]+red[6]+red[7];
    float m = S*(1.f/768.f);
    float var = S2*(1.f/768.f) - m*m;
    stat[0]=m; stat[1]=rsqrtf(var + 1e-5f);
  }
  __syncthreads();
  float m=stat[0], inv=stat[1];
  for (int d=threadIdx.x; d<768; d+=256)
    o[d] = __float2bfloat16((x[d]-m)*inv*g[d] + b[d]);
}

// ---------------- router v2: one wave per row, x cached in registers ----------------
template<int K>
__global__ __launch_bounds__(256) void router2(const bf16* __restrict__ X,
    const float* __restrict__ W, const float* __restrict__ bias,
    float* __restrict__ out, int rows){
  int row = blockIdx.x*4 + (threadIdx.x>>6);
  int lane = threadIdx.x & 63;
  if (row >= rows) return;               // wave-uniform
  const bf16* x = X + (size_t)row*K;
  constexpr int NC = K/64;
  float xa[NC];
  #pragma unroll
  for (int c=0;c<NC;++c) xa[c] = b2f(x[c*64 + lane]);
  float lg[5];
  #pragma unroll
  for (int e=0;e<5;++e){
    const float* w = W + (size_t)e*K;
    float p=0.f;
    #pragma unroll
    for (int c=0;c<NC;++c) p += xa[c]*w[c*64 + lane];
    lg[e] = wave_sum(p);
  }
  if (lane==0){
    float mx=-1e30f;
    #pragma unroll
    for (int e=0;e<5;++e){ lg[e] += bias[e]; mx = fmaxf(mx, lg[e]); }
    float s=0.f;
    #pragma unroll
    for (int e=0;e<5;++e){ lg[e]=expf(lg[e]-mx); s+=lg[e]; }
    float inv=1.f/s;
    #pragma unroll
    for (int e=0;e<5;++e) out[(size_t)row*5+e] = lg[e]*inv;
  }
}

// ---------------- msg attention: seq=8 within each b, 12 heads (fp32) ----------------
__global__ __launch_bounds__(64) void msg_attn(const float* __restrict__ mqkv,
    float* __restrict__ mattno){
  int bh = blockIdx.x; int b = bh/12, h = bh%12;
  __shared__ float qs[8][64], ks[8][64], vs[8][64], sc[8][8];
  int lane = threadIdx.x;
  for (int i=lane; i<512; i+=64){
    int t=i>>6, d=i&63;
    size_t base = ((size_t)(b*8+t))*2304 + h*64 + d;
    qs[t][d]=mqkv[base]; ks[t][d]=mqkv[base+768]; vs[t][d]=mqkv[base+1536];
  }
  __syncthreads();
  { int t=lane>>3, m=lane&7; float a=0.f;
    #pragma unroll
    for (int d=0;d<64;++d) a += qs[t][d]*ks[m][d];
    sc[t][m] = a*0.125f; }
  __syncthreads();
  if (lane<8){
    int t=lane; float mx=-1e30f;
    #pragma unroll
    for (int m=0;m<8;++m) mx=fmaxf(mx, sc[t][m]);
    float s=0.f;
    #pragma unroll
    for (int m=0;m<8;++m){ float e=expf(sc[t][m]-mx); sc[t][m]=e; s+=e; }
    float inv=1.f/s;
    #pragma unroll
    for (int m=0;m<8;++m) sc[t][m]*=inv;
  }
  __syncthreads();
  { int t=lane>>3, d0=(lane&7)*8;
    for (int dd=0; dd<8; ++dd){
      int d=d0+dd; float a=0.f;
      #pragma unroll
      for (int m=0;m<8;++m) a += sc[t][m]*vs[m][d];
      mattno[((size_t)(b*8+t))*768 + h*64 + d] = a;
    } }
}

// ================ MFMA attention: seq=198, D=64; block = (bb,h) x 64 q-rows ================
// grid (384, 4), 256 threads (4 waves x 16 q-rows).
__global__ __launch_bounds__(256) void attn_mfma(const bf16* __restrict__ qkv,
    bf16* __restrict__ attno){
  constexpr int KP = 232;                 // padded key stride (2-way-conflict-free)
  __shared__ __align__(16) unsigned short Ks[208*72];   // K [key][d], stride 72
  __shared__ __align__(16) unsigned short Vt[64*KP];    // V^T [d][key]
  __shared__ __align__(16) unsigned short Ps[4*16*KP];  // P per wave [qrow][key]

  int tid = threadIdx.x;
  int bh = blockIdx.x; int bb = bh/12, h = bh%12;
  int l0 = blockIdx.y*64;
  int wv = tid>>6, ln = tid&63, quad = ln>>4, mrow = ln&15;

  // ---- stage K [key][d] and V^T [d][key] ----
  for (int i=tid; i<1584; i+=256){        // 198 rows x 8 chunks of 8 bf16
    int m=i>>3, dc=(i&7)<<3;
    const uint4 kv = *reinterpret_cast<const uint4*>(qkv + ((size_t)(m*32+bb))*2304 + 768 + h*64 + dc);
    *reinterpret_cast<uint4*>(Ks + m*72 + dc) = kv;
    const uint4 vv = *reinterpret_cast<const uint4*>(qkv + ((size_t)(m*32+bb))*2304 + 1536 + h*64 + dc);
    unsigned int w[4] = {vv.x, vv.y, vv.z, vv.w};
    #pragma unroll
    for (int j=0;j<4;++j){
      Vt[(dc+2*j  )*KP + m] = (unsigned short)(w[j] & 0xffff);
      Vt[(dc+2*j+1)*KP + m] = (unsigned short)(w[j] >> 16);
    }
  }
  for (int i=tid; i<10*72; i+=256) Ks[198*72 + i] = 0;          // zero pad keys 198..207
  for (int i=tid; i<64*34; i+=256){ int d=i/34, c=198+(i%34); Vt[d*KP+c] = 0; }
  { unsigned int* pz = reinterpret_cast<unsigned int*>(Ps);
    for (int i=tid; i<4*16*KP/2; i+=256) pz[i] = 0; }

  // ---- Q fragments (direct from global) ----
  int ql = l0 + wv*16 + mrow;
  short8 aq[2] = { {0,0,0,0,0,0,0,0}, {0,0,0,0,0,0,0,0} };
  if (ql < 198){
    aq[0] = *reinterpret_cast<const short8*>(qkv + ((size_t)(ql*32+bb))*2304 + h*64 + quad*8);
    aq[1] = *reinterpret_cast<const short8*>(qkv + ((size_t)(ql*32+bb))*2304 + h*64 + 32 + quad*8);
  }
  __syncthreads();

  // ---- scores: S = Q K^T * 0.125 ----
  f32x4 sc[13];
  const f32x4 zero = {0.f,0.f,0.f,0.f};
  #pragma unroll
  for (int t=0;t<13;++t){
    const short8 bk0 = *reinterpret_cast<const short8*>(Ks + (t*16+mrow)*72 + quad*8);
    const short8 bk1 = *reinterpret_cast<const short8*>(Ks + (t*16+mrow)*72 + 32 + quad*8);
    f32x4 a = zero;
    a = __builtin_amdgcn_mfma_f32_16x16x32_bf16(aq[0], bk0, a, 0,0,0);
    a = __builtin_amdgcn_mfma_f32_16x16x32_bf16(aq[1], bk1, a, 0,0,0);
    sc[t] = a * 0.125f;
  }
  if (192 + mrow >= 198) sc[12] = (f32x4){-1e30f,-1e30f,-1e30f,-1e30f};

  // ---- softmax over keys (rows distributed: row=quad*4+r, cols=lane&15 across tiles) ----
  float inv[4];
  #pragma unroll
  for (int r=0;r<4;++r){
    float m = -1e30f;
    #pragma unroll
    for (int t=0;t<13;++t) m = fmaxf(m, sc[t][r]);
    #pragma unroll
    for (int msk=1; msk<16; msk<<=1) m = fmaxf(m, __shfl_xor(m, msk));
    float s = 0.f;
    #pragma unroll
    for (int t=0;t<13;++t){ float e = __expf(sc[t][r]-m); sc[t][r]=e; s+=e; }
    #pragma unroll
    for (int msk=1; msk<16; msk<<=1) s += __shfl_xor(s, msk);
    inv[r] = 1.f/s;
  }

  // ---- write P (bf16) to LDS in A-layout source (row-major [qrow][key]) ----
  #pragma unroll
  for (int t=0;t<13;++t)
    #pragma unroll
    for (int r=0;r<4;++r)
      Ps[(wv*16 + quad*4+r)*KP + t*16+mrow] = f2bits(sc[t][r]);
  __syncthreads();

  // ---- O = P V (normalization folded into store) ----
  f32x4 o[4] = {zero,zero,zero,zero};
  #pragma unroll
  for (int kc=0;kc<7;++kc){
    const short8 ap = *reinterpret_cast<const short8*>(Ps + (wv*16+mrow)*KP + kc*32 + quad*8);
    #pragma unroll
    for (int nt=0;nt<4;++nt){
      const short8 bv = *reinterpret_cast<const short8*>(Vt + (nt*16+mrow)*KP + kc*32 + quad*8);
      o[nt] = __builtin_amdgcn_mfma_f32_16x16x32_bf16(ap, bv, o[nt], 0,0,0);
    }
  }
  #pragma unroll
  for (int r=0;r<4;++r){
    int l = l0 + wv*16 + quad*4 + r;
    if (l >= 198) continue;
    #pragma unroll
    for (int nt=0;nt<4;++nt){
      int d = nt*16 + mrow;
      attno[((size_t)(l*32+bb))*768 + h*64 + d] = __float2bfloat16(o[nt][r]*inv[r]);
    }
  }
}

// ---------------- small fp32 tiled GEMM for msg branch ----------------
__global__ __launch_bounds__(256) void gemm_nt(const float* __restrict__ A,
    const float* __restrict__ B, const float* __restrict__ bias,
    const float* res, float* C,
    int M, int N, int K){
  __shared__ __align__(16) float As[16][68];
  __shared__ __align__(16) float Bs[16][68];
  int tid=threadIdx.x, tx=tid&15, ty=tid>>4;
  int row0=blockIdx.y*64, col0=blockIdx.x*64;
  int lrow=tid>>2, lk4=(tid&3)*4;
  float acc[4][4]={};
  for (int kb=0; kb<K; kb+=16){
    int gr = row0 + lrow;
    if (gr < M){
      float a0,a1,a2,a3; ld4(A + (size_t)gr*K + kb + lk4, a0,a1,a2,a3);
      As[lk4][lrow]=a0; As[lk4+1][lrow]=a1; As[lk4+2][lrow]=a2; As[lk4+3][lrow]=a3;
    } else {
      As[lk4][lrow]=0.f; As[lk4+1][lrow]=0.f; As[lk4+2][lrow]=0.f; As[lk4+3][lrow]=0.f;
    }
    { float c0,c1,c2,c3; ld4(B + (size_t)(col0+lrow)*K + kb + lk4, c0,c1,c2,c3);
      Bs[lk4][lrow]=c0; Bs[lk4+1][lrow]=c1; Bs[lk4+2][lrow]=c2; Bs[lk4+3][lrow]=c3; }
    __syncthreads();
    #pragma unroll
    for (int kk=0;kk<16;++kk){
      float4 a4 = *reinterpret_cast<const float4*>(&As[kk][ty*4]);
      float4 b4 = *reinterpret_cast<const float4*>(&Bs[kk][tx*4]);
      float av[4]={a4.x,a4.y,a4.z,a4.w};
      float bw[4]={b4.x,b4.y,b4.z,b4.w};
      #pragma unroll
      for (int u=0;u<4;++u)
        #pragma unroll
        for (int v=0;v<4;++v) acc[u][v] += av[u]*bw[v];
    }
    __syncthreads();
  }
  #pragma unroll
  for (int u=0;u<4;++u){
    int gi = row0 + ty*4 + u;
    if (gi >= M) continue;
    #pragma unroll
    for (int v=0;v<4;++v){
      int gj = col0 + tx*4 + v;
      float r = res ? res[(size_t)gi*N+gj] : 0.f;
      float bb = bias ? bias[gj] : 0.f;
      C[(size_t)gi*N+gj] = r + acc[u][v] + bb;
    }
  }
}

// ================= MFMA bf16 GEMM, 128x128 tile, BK=32 (m97 recipe) =================
// MODE 0 (QKV): +bias -> bf16 | MODE 1 (WO): +bias+res -> f32
// MODE 2 (HEADS): sum_e r_e(acc+bias_e), qgelu -> bf16 | MODE 3 (TAILS): sum_e r_e(acc+bias_e)+res -> f32
template<int MODE>
__global__ __launch_bounds__(256,2) void gemm_mfma(
    const bf16* __restrict__ A, const bf16* __restrict__ B,
    const float* __restrict__ bias, const float* __restrict__ rmat,
    const float* __restrict__ res, float* __restrict__ outf,
    bf16* __restrict__ outb, int M, int N, int K)
{
  constexpr int NE = (MODE>=2) ? 5 : 1;
  __shared__ __align__(16) bf16 As[128*32];
  __shared__ __align__(16) bf16 Bs[128*32];
  __shared__ float rls[(MODE>=2) ? 640 : 4];

  int tid=threadIdx.x, wv=tid>>6, ln=tid&63;
  int quad=ln>>4, mrow=ln&15;
  int row0=blockIdx.y*128, col0=blockIdx.x*128;
  int wr=wv>>1, wc=wv&1;

  if (MODE>=2){
    for (int i=tid; i<640; i+=256) rls[i] = rmat[(size_t)row0*5 + i];
  }

  int c0 = wv*64 + ln;
  int r0 = c0>>2, cc=(c0&3)*8;
  bf16* lA0 = As + wv*512;
  bf16* lA1 = As + 2048 + wv*512;
  bf16* lB0 = Bs + wv*512;
  bf16* lB1 = Bs + 2048 + wv*512;

  int aoff[4], boff[4];
  #pragma unroll
  for (int i=0;i<4;++i){
    aoff[i] = (wr*64 + i*16 + mrow)*32 + quad*8;
    boff[i] = (wc*64 + i*16 + mrow)*32 + quad*8;
  }

  float tot[4][4][4];
  if (MODE>=2){
    #pragma unroll
    for (int i=0;i<4;++i)
      #pragma unroll
      for (int j=0;j<4;++j)
        #pragma unroll
        for (int r=0;r<4;++r) tot[i][j][r]=0.f;
  }
  f32x4 acc[4][4];
  const f32x4 zero = {0.f,0.f,0.f,0.f};

  for (int e=0;e<NE;++e){
    const bf16* Be = B + (size_t)e*N*K;
    #pragma unroll
    for (int i=0;i<4;++i)
      #pragma unroll
      for (int j=0;j<4;++j) acc[i][j]=zero;

    const bf16* Ab = A + (size_t)(row0+r0)*K + cc;
    const bf16* Bb = Be + (size_t)(col0+r0)*K + cc;
    for (int kb=0; kb<K; kb+=32){
      gload16(Ab + kb, lA0);
      gload16(Ab + (size_t)64*K + kb, lA1);
      gload16(Bb + kb, lB0);
      gload16(Bb + (size_t)64*K + kb, lB1);
      __syncthreads();
      short8 af[4], bfr[4];
      #pragma unroll
      for (int i=0;i<4;++i) af[i]  = *reinterpret_cast<const short8*>(As + aoff[i]);
      #pragma unroll
      for (int j=0;j<4;++j) bfr[j] = *reinterpret_cast<const short8*>(Bs + boff[j]);
      #pragma unroll
      for (int i=0;i<4;++i)
        #pragma unroll
        for (int j=0;j<4;++j)
          acc[i][j] = __builtin_amdgcn_mfma_f32_16x16x32_bf16(af[i], bfr[j], acc[i][j], 0, 0, 0);
      __syncthreads();
    }
    if (MODE>=2){
      #pragma unroll
      for (int i=0;i<4;++i){
        #pragma unroll
        for (int r=0;r<4;++r){
          int lr = wr*64 + i*16 + quad*4 + r;
          float w = rls[lr*5+e];
          #pragma unroll
          for (int j=0;j<4;++j){
            int gc = col0 + wc*64 + j*16 + mrow;
            tot[i][j][r] += w*(acc[i][j][r] + bias[e*N + gc]);
          }
        }
      }
    }
  }

  #pragma unroll
  for (int i=0;i<4;++i){
    #pragma unroll
    for (int r=0;r<4;++r){
      int gi = row0 + wr*64 + i*16 + quad*4 + r;
      if (gi >= M) continue;
      #pragma unroll
      for (int j=0;j<4;++j){
        int gj = col0 + wc*64 + j*16 + mrow;
        float v;
        if (MODE==0)      v = acc[i][j][r] + bias[gj];
        else if (MODE==1) v = acc[i][j][r] + bias[gj] + res[(size_t)gi*N+gj];
        else if (MODE==2){ float x = tot[i][j][r]; v = x/(1.f+expf(-1.702f*x)); }
        else              v = tot[i][j][r] + res[(size_t)gi*N+gj];
        if (MODE==0 || MODE==2) outb[(size_t)gi*N+gj] = __float2bfloat16(v);
        else                    outf[(size_t)gi*N+gj] = v;
      }
    }
  }
}

extern "C" void kernel_launch(void* const* d_in, const int* in_sizes, int n_in,
                              void* d_out, int out_size, void* d_ws, size_t ws_size,
                              hipStream_t stream) {
  const float* x         = (const float*)d_in[0];
  const float* msg_fc_w  = (const float*)d_in[1];
  const float* msg_fc_b  = (const float*)d_in[2];
  const float* msg_ln_g  = (const float*)d_in[3];
  const float* msg_ln_b  = (const float*)d_in[4];
  const float* msg_wqkv  = (const float*)d_in[5];
  const float* msg_bqkv  = (const float*)d_in[6];
  const float* msg_wo    = (const float*)d_in[7];
  const float* msg_bo    = (const float*)d_in[8];
  const float* attn_wqkv = (const float*)d_in[9];
  const float* attn_bqkv = (const float*)d_in[10];
  const float* attn_wo   = (const float*)d_in[11];
  const float* attn_bo   = (const float*)d_in[12];
  const float* ln1_g     = (const float*)d_in[13];
  const float* ln1_b     = (const float*)d_in[14];
  const float* ln2_g     = (const float*)d_in[15];
  const float* ln2_b     = (const float*)d_in[16];
  const float* cfc_w     = (const float*)d_in[17];
  const float* cfc_b     = (const float*)d_in[18];
  const float* cproj_w   = (const float*)d_in[19];
  const float* cproj_b   = (const float*)d_in[20];
  const float* eh_w      = (const float*)d_in[21];
  const float* eh_b      = (const float*)d_in[22];
  const float* et_w      = (const float*)d_in[23];
  const float* et_b      = (const float*)d_in[24];
  const float* r1_w      = (const float*)d_in[25];
  const float* r1_b      = (const float*)d_in[26];
  const float* r2_w      = (const float*)d_in[27];
  const float* r2_b      = (const float*)d_in[28];
  float* out = (float*)d_out;

  // ---- workspace layout (float units) ----
  float* ws     = (float*)d_ws;
  float* xc     = ws;                        // 6336*768 f32
  float* bigA   = xc + 4866048;
  bf16*  qkv_b  = (bf16*)bigA;               // qkv: 6400*2304 bf16
  bf16*  oh_b   = (bf16*)bigA;               // oh : 6400*3072 bf16 (reuse)
  float* lnbf   = bigA + 9830400;
  bf16*  lnb_b  = (bf16*)lnbf;
  float* attnof = lnbf + 2457600;
  bf16*  attno_b= (bf16*)attnof;
  float* wqf    = attnof + 2457600;
  bf16*  wq_b   = (bf16*)wqf;
  float* wof    = wqf + 884736;
  bf16*  wo_b   = (bf16*)wof;
  float* whf    = wof + 294912;
  bf16*  wh_b   = (bf16*)whf;
  float* wtf    = whf + 5898240;
  bf16*  wt_b   = (bf16*)wtf;
  float* bias_h = wtf + 5898240;
  float* bias_t = bias_h + 15360;
  float* r1b    = bias_t + 3840;
  float* r2b    = r1b + 32000;
  float* msg    = r2b + 32000;
  float* mln    = msg + 24576;
  float* mqkv   = mln + 24576;
  float* matt   = mqkv + 73728;

  // ---- weight conversions fp32 -> bf16 (and bias concat) ----
  cvt_f2b<<<dim3(1769472/4/256), 256, 0, stream>>>(attn_wqkv, wq_b, 1769472);
  cvt_f2b<<<dim3(589824/4/256), 256, 0, stream>>>(attn_wo, wo_b, 589824);
  cvt_f2b<<<dim3(2359296/4/256), 256, 0, stream>>>(cfc_w, wh_b, 2359296);
  cvt_f2b<<<dim3(9437184/4/256), 256, 0, stream>>>(eh_w, wh_b + 2359296, 9437184);
  cvt_f2b<<<dim3(2359296/4/256), 256, 0, stream>>>(cproj_w, wt_b, 2359296);
  cvt_f2b<<<dim3(9437184/4/256), 256, 0, stream>>>(et_w, wt_b + 2359296, 9437184);
  hipMemcpyAsync(bias_h,        cfc_b,   3072*sizeof(float), hipMemcpyDeviceToDevice, stream);
  hipMemcpyAsync(bias_h+3072,   eh_b,   12288*sizeof(float), hipMemcpyDeviceToDevice, stream);
  hipMemcpyAsync(bias_t,        cproj_b,  768*sizeof(float), hipMemcpyDeviceToDevice, stream);
  hipMemcpyAsync(bias_t+768,    et_b,    3072*sizeof(float), hipMemcpyDeviceToDevice, stream);

  // 1. xc[0:6304] = x
  hipMemcpyAsync(xc, x, (size_t)4841472*sizeof(float), hipMemcpyDeviceToDevice, stream);
  // 2. msg branch (fp32, tiny)
  gemm_nt<<<dim3(12,1), 256, 0, stream>>>(x, msg_fc_w, msg_fc_b, nullptr, msg, 32, 768, 768);
  ln_rows<<<dim3(32), 256, 0, stream>>>(msg, msg_ln_g, msg_ln_b, mln);
  gemm_nt<<<dim3(36,1), 256, 0, stream>>>(mln, msg_wqkv, msg_bqkv, nullptr, mqkv, 32, 2304, 768);
  msg_attn<<<dim3(48), 64, 0, stream>>>(mqkv, matt);
  gemm_nt<<<dim3(12,1), 256, 0, stream>>>(matt, msg_wo, msg_bo, msg, xc + (size_t)6304*768, 32, 768, 768);
  // 3. ln1 (6336 rows) -> bf16
  ln_rows_b<<<dim3(6336), 256, 0, stream>>>(xc, ln1_g, ln1_b, lnb_b);
  // 4. qkv = ln1 @ Wqkv^T + b (MFMA)
  gemm_mfma<0><<<dim3(18,50), 256, 0, stream>>>(lnb_b, wq_b, attn_bqkv, nullptr, nullptr, nullptr, qkv_b, 6336, 2304, 768);
  // 5. MFMA attention
  attn_mfma<<<dim3(384,4), 256, 0, stream>>>(qkv_b, attno_b);
  // 6. xc += attno @ Wo^T + bo (MFMA)
  gemm_mfma<1><<<dim3(6,50), 256, 0, stream>>>(attno_b, wo_b, attn_bo, nullptr, xc, xc, nullptr, 6336, 768, 768);
  // 7. ln2 (6304 rows) -> bf16
  ln_rows_b<<<dim3(6304), 256, 0, stream>>>(xc, ln2_g, ln2_b, lnb_b);
  // 8. r1 router
  router2<768><<<dim3(1576), 256, 0, stream>>>(lnb_b, r1_w, r1_b, r1b, 6304);
  // 9. heads MoE GEMM -> oh (bf16, qgelu)
  gemm_mfma<2><<<dim3(24,50), 256, 0, stream>>>(lnb_b, wh_b, bias_h, r1b, nullptr, nullptr, oh_b, 6304, 3072, 768);
  // 10. r2 router (K=3072)
  router2<3072><<<dim3(1576), 256, 0, stream>>>(oh_b, r2_w, r2_b, r2b, 6304);
  // 11. tails MoE GEMM + residual -> out (f32)
  gemm_mfma<3><<<dim3(6,50), 256, 0, stream>>>(oh_b, wt_b, bias_t, r2b, xc, out, nullptr, 6304, 768, 3072);
}

// Round 5
// 1219.402 us; speedup vs baseline: 4.7690x; 1.1014x over previous
//
#include <hip/hip_runtime.h>
#include <hip/hip_bf16.h>

typedef __hip_bfloat16 bf16;
typedef __attribute__((ext_vector_type(8))) short short8;
typedef __attribute__((ext_vector_type(4))) float f32x4;

__device__ __forceinline__ float b2f(bf16 v){ return __bfloat162float(v); }
__device__ __forceinline__ unsigned short f2bits(float v){
  bf16 h = __float2bfloat16(v);
  return *reinterpret_cast<unsigned short*>(&h);
}

__device__ __forceinline__ void gload16(const bf16* g, bf16* l){
  __builtin_amdgcn_global_load_lds((const __attribute__((address_space(1))) void*)g,
                                   (__attribute__((address_space(3))) void*)l, 16, 0, 0);
}

__device__ __forceinline__ void ld4(const float* p, float& a,float& b,float& c,float& d){
  float4 v = *reinterpret_cast<const float4*>(p); a=v.x; b=v.y; c=v.z; d=v.w;
}
__device__ __forceinline__ float wave_sum(float v){
  #pragma unroll
  for (int off=32; off>0; off>>=1) v += __shfl_down(v, off);
  return v;
}

// ---------------- fused weight prep: fp32 -> bf16 for 6 weight tensors ----------------
__global__ __launch_bounds__(256) void prep_weights(
    const float* __restrict__ s0, const float* __restrict__ s1,
    const float* __restrict__ s2, const float* __restrict__ s3,
    const float* __restrict__ s4, const float* __restrict__ s5,
    bf16* __restrict__ d0, bf16* __restrict__ d1, bf16* __restrict__ d2,
    bf16* __restrict__ d3, bf16* __restrict__ d4, bf16* __restrict__ d5){
  // vec4 prefix: wq 442368 | wo 147456 | cfc 589824 | eh 2359296 | cproj 589824 | et 2359296
  long i4 = (long)blockIdx.x*256 + threadIdx.x;
  const float* s; bf16* d; long base;
  if      (i4 <  442368){ s=s0; d=d0; base=0; }
  else if (i4 <  589824){ s=s1; d=d1; base=442368; }
  else if (i4 < 1179648){ s=s2; d=d2; base=589824; }
  else if (i4 < 3538944){ s=s3; d=d3; base=1179648; }
  else if (i4 < 4128768){ s=s4; d=d4; base=3538944; }
  else                  { s=s5; d=d5; base=4128768; }
  long j = (i4 - base)*4;
  float4 v = *reinterpret_cast<const float4*>(s + j);
  d[j]   = __float2bfloat16(v.x);
  d[j+1] = __float2bfloat16(v.y);
  d[j+2] = __float2bfloat16(v.z);
  d[j+3] = __float2bfloat16(v.w);
}

// ---------------- fused bias concat (f32 copies) ----------------
__global__ __launch_bounds__(256) void prep_bias(
    const float* __restrict__ cfc_b, const float* __restrict__ eh_b,
    const float* __restrict__ cproj_b, const float* __restrict__ et_b,
    float* __restrict__ bias_h, float* __restrict__ bias_t){
  int i = blockIdx.x*256 + threadIdx.x;   // 19200 total
  if (i < 3072)       bias_h[i] = cfc_b[i];
  else if (i < 15360) bias_h[i] = eh_b[i-3072];
  else if (i < 16128) bias_t[i-15360] = cproj_b[i-15360];
  else if (i < 19200) bias_t[i-15360] = et_b[i-16128];
}

// ---------------- row LayerNorm: fp32 in, fp32 out ----------------
__global__ __launch_bounds__(256) void ln_rows(const float* __restrict__ in,
    const float* __restrict__ g, const float* __restrict__ b,
    float* __restrict__ out){
  int row = blockIdx.x;
  const float* x = in + (size_t)row*768;
  float* o = out + (size_t)row*768;
  float s=0.f, s2=0.f;
  for (int d=threadIdx.x; d<768; d+=256){ float v=x[d]; s+=v; s2+=v*v; }
  s = wave_sum(s); s2 = wave_sum(s2);
  __shared__ float red[8];
  __shared__ float stat[2];
  int lane = threadIdx.x & 63, wid = threadIdx.x >> 6;
  if (lane==0){ red[wid]=s; red[4+wid]=s2; }
  __syncthreads();
  if (threadIdx.x==0){
    float S=red[0]+red[1]+red[2]+red[3];
    float S2=red[4]+red[5]+red[6]+red[7];
    float m = S*(1.f/768.f);
    float var = S2*(1.f/768.f) - m*m;
    stat[0]=m; stat[1]=rsqrtf(var + 1e-5f);
  }
  __syncthreads();
  float m=stat[0], inv=stat[1];
  for (int d=threadIdx.x; d<768; d+=256)
    o[d] = (x[d]-m)*inv*g[d] + b[d];
}

// ---------------- row LayerNorm: fp32 in, bf16 out ----------------
__global__ __launch_bounds__(256) void ln_rows_b(const float* __restrict__ in,
    const float* __restrict__ g, const float* __restrict__ b,
    bf16* __restrict__ out){
  int row = blockIdx.x;
  const float* x = in + (size_t)row*768;
  bf16* o = out + (size_t)row*768;
  float s=0.f, s2=0.f;
  for (int d=threadIdx.x; d<768; d+=256){ float v=x[d]; s+=v; s2+=v*v; }
  s = wave_sum(s); s2 = wave_sum(s2);
  __shared__ float red[8];
  __shared__ float stat[2];
  int lane = threadIdx.x & 63, wid = threadIdx.x >> 6;
  if (lane==0){ red[wid]=s; red[4+wid]=s2; }
  __syncthreads();
  if (threadIdx.x==0){
    float S=red[0]+red[1]+red[2]+red[3];
    float S2=red[4]+red[5]+red[6]+red[7];
    float m = S*(1.f/768.f);
    float var = S2*(1.f/768.f) - m*m;
    stat[0]=m; stat[1]=rsqrtf(var + 1e-5f);
  }
  __syncthreads();
  float m=stat[0], inv=stat[1];
  for (int d=threadIdx.x; d<768; d+=256)
    o[d] = __float2bfloat16((x[d]-m)*inv*g[d] + b[d]);
}

// ---------------- router: one wave per row, x cached in registers ----------------
template<int K>
__global__ __launch_bounds__(256) void router2(const bf16* __restrict__ X,
    const float* __restrict__ W, const float* __restrict__ bias,
    float* __restrict__ out, int rows){
  int row = blockIdx.x*4 + (threadIdx.x>>6);
  int lane = threadIdx.x & 63;
  if (row >= rows) return;               // wave-uniform
  const bf16* x = X + (size_t)row*K;
  constexpr int NC = K/64;
  float xa[NC];
  #pragma unroll
  for (int c=0;c<NC;++c) xa[c] = b2f(x[c*64 + lane]);
  float lg[5];
  #pragma unroll
  for (int e=0;e<5;++e){
    const float* w = W + (size_t)e*K;
    float p=0.f;
    #pragma unroll
    for (int c=0;c<NC;++c) p += xa[c]*w[c*64 + lane];
    lg[e] = wave_sum(p);
  }
  if (lane==0){
    float mx=-1e30f;
    #pragma unroll
    for (int e=0;e<5;++e){ lg[e] += bias[e]; mx = fmaxf(mx, lg[e]); }
    float s=0.f;
    #pragma unroll
    for (int e=0;e<5;++e){ lg[e]=expf(lg[e]-mx); s+=lg[e]; }
    float inv=1.f/s;
    #pragma unroll
    for (int e=0;e<5;++e) out[(size_t)row*5+e] = lg[e]*inv;
  }
}

// ---------------- msg attention: seq=8 within each b, 12 heads (fp32) ----------------
__global__ __launch_bounds__(64) void msg_attn(const float* __restrict__ mqkv,
    float* __restrict__ mattno){
  int bh = blockIdx.x; int b = bh/12, h = bh%12;
  __shared__ float qs[8][64], ks[8][64], vs[8][64], sc[8][8];
  int lane = threadIdx.x;
  for (int i=lane; i<512; i+=64){
    int t=i>>6, d=i&63;
    size_t base = ((size_t)(b*8+t))*2304 + h*64 + d;
    qs[t][d]=mqkv[base]; ks[t][d]=mqkv[base+768]; vs[t][d]=mqkv[base+1536];
  }
  __syncthreads();
  { int t=lane>>3, m=lane&7; float a=0.f;
    #pragma unroll
    for (int d=0;d<64;++d) a += qs[t][d]*ks[m][d];
    sc[t][m] = a*0.125f; }
  __syncthreads();
  if (lane<8){
    int t=lane; float mx=-1e30f;
    #pragma unroll
    for (int m=0;m<8;++m) mx=fmaxf(mx, sc[t][m]);
    float s=0.f;
    #pragma unroll
    for (int m=0;m<8;++m){ float e=expf(sc[t][m]-mx); sc[t][m]=e; s+=e; }
    float inv=1.f/s;
    #pragma unroll
    for (int m=0;m<8;++m) sc[t][m]*=inv;
  }
  __syncthreads();
  { int t=lane>>3, d0=(lane&7)*8;
    for (int dd=0; dd<8; ++dd){
      int d=d0+dd; float a=0.f;
      #pragma unroll
      for (int m=0;m<8;++m) a += sc[t][m]*vs[m][d];
      mattno[((size_t)(b*8+t))*768 + h*64 + d] = a;
    } }
}

// ================ MFMA attention: seq=198, D=64; block = (bb,h) x 64 q-rows ================
__global__ __launch_bounds__(256) void attn_mfma(const bf16* __restrict__ qkv,
    bf16* __restrict__ attno){
  constexpr int KP = 232;
  __shared__ __align__(16) unsigned short Ks[208*72];
  __shared__ __align__(16) unsigned short Vt[64*KP];
  __shared__ __align__(16) unsigned short Ps[4*16*KP];

  int tid = threadIdx.x;
  int bh = blockIdx.x; int bb = bh/12, h = bh%12;
  int l0 = blockIdx.y*64;
  int wv = tid>>6, ln = tid&63, quad = ln>>4, mrow = ln&15;

  for (int i=tid; i<1584; i+=256){
    int m=i>>3, dc=(i&7)<<3;
    const uint4 kv = *reinterpret_cast<const uint4*>(qkv + ((size_t)(m*32+bb))*2304 + 768 + h*64 + dc);
    *reinterpret_cast<uint4*>(Ks + m*72 + dc) = kv;
    const uint4 vv = *reinterpret_cast<const uint4*>(qkv + ((size_t)(m*32+bb))*2304 + 1536 + h*64 + dc);
    unsigned int w[4] = {vv.x, vv.y, vv.z, vv.w};
    #pragma unroll
    for (int j=0;j<4;++j){
      Vt[(dc+2*j  )*KP + m] = (unsigned short)(w[j] & 0xffff);
      Vt[(dc+2*j+1)*KP + m] = (unsigned short)(w[j] >> 16);
    }
  }
  for (int i=tid; i<10*72; i+=256) Ks[198*72 + i] = 0;
  for (int i=tid; i<64*34; i+=256){ int d=i/34, c=198+(i%34); Vt[d*KP+c] = 0; }
  { unsigned int* pz = reinterpret_cast<unsigned int*>(Ps);
    for (int i=tid; i<4*16*KP/2; i+=256) pz[i] = 0; }

  int ql = l0 + wv*16 + mrow;
  short8 aq[2] = { {0,0,0,0,0,0,0,0}, {0,0,0,0,0,0,0,0} };
  if (ql < 198){
    aq[0] = *reinterpret_cast<const short8*>(qkv + ((size_t)(ql*32+bb))*2304 + h*64 + quad*8);
    aq[1] = *reinterpret_cast<const short8*>(qkv + ((size_t)(ql*32+bb))*2304 + h*64 + 32 + quad*8);
  }
  __syncthreads();

  f32x4 sc[13];
  const f32x4 zero = {0.f,0.f,0.f,0.f};
  #pragma unroll
  for (int t=0;t<13;++t){
    const short8 bk0 = *reinterpret_cast<const short8*>(Ks + (t*16+mrow)*72 + quad*8);
    const short8 bk1 = *reinterpret_cast<const short8*>(Ks + (t*16+mrow)*72 + 32 + quad*8);
    f32x4 a = zero;
    a = __builtin_amdgcn_mfma_f32_16x16x32_bf16(aq[0], bk0, a, 0,0,0);
    a = __builtin_amdgcn_mfma_f32_16x16x32_bf16(aq[1], bk1, a, 0,0,0);
    sc[t] = a * 0.125f;
  }
  if (192 + mrow >= 198) sc[12] = (f32x4){-1e30f,-1e30f,-1e30f,-1e30f};

  float inv[4];
  #pragma unroll
  for (int r=0;r<4;++r){
    float m = -1e30f;
    #pragma unroll
    for (int t=0;t<13;++t) m = fmaxf(m, sc[t][r]);
    #pragma unroll
    for (int msk=1; msk<16; msk<<=1) m = fmaxf(m, __shfl_xor(m, msk));
    float s = 0.f;
    #pragma unroll
    for (int t=0;t<13;++t){ float e = __expf(sc[t][r]-m); sc[t][r]=e; s+=e; }
    #pragma unroll
    for (int msk=1; msk<16; msk<<=1) s += __shfl_xor(s, msk);
    inv[r] = 1.f/s;
  }

  #pragma unroll
  for (int t=0;t<13;++t)
    #pragma unroll
    for (int r=0;r<4;++r)
      Ps[(wv*16 + quad*4+r)*KP + t*16+mrow] = f2bits(sc[t][r]);
  __syncthreads();

  f32x4 o[4] = {zero,zero,zero,zero};
  #pragma unroll
  for (int kc=0;kc<7;++kc){
    const short8 ap = *reinterpret_cast<const short8*>(Ps + (wv*16+mrow)*KP + kc*32 + quad*8);
    #pragma unroll
    for (int nt=0;nt<4;++nt){
      const short8 bv = *reinterpret_cast<const short8*>(Vt + (nt*16+mrow)*KP + kc*32 + quad*8);
      o[nt] = __builtin_amdgcn_mfma_f32_16x16x32_bf16(ap, bv, o[nt], 0,0,0);
    }
  }
  #pragma unroll
  for (int r=0;r<4;++r){
    int l = l0 + wv*16 + quad*4 + r;
    if (l >= 198) continue;
    #pragma unroll
    for (int nt=0;nt<4;++nt){
      int d = nt*16 + mrow;
      attno[((size_t)(l*32+bb))*768 + h*64 + d] = __float2bfloat16(o[nt][r]*inv[r]);
    }
  }
}

// ---------------- small fp32 tiled GEMM for msg branch ----------------
__global__ __launch_bounds__(256) void gemm_nt(const float* __restrict__ A,
    const float* __restrict__ B, const float* __restrict__ bias,
    const float* res, float* C,
    int M, int N, int K){
  __shared__ __align__(16) float As[16][68];
  __shared__ __align__(16) float Bs[16][68];
  int tid=threadIdx.x, tx=tid&15, ty=tid>>4;
  int row0=blockIdx.y*64, col0=blockIdx.x*64;
  int lrow=tid>>2, lk4=(tid&3)*4;
  float acc[4][4]={};
  for (int kb=0; kb<K; kb+=16){
    int gr = row0 + lrow;
    if (gr < M){
      float a0,a1,a2,a3; ld4(A + (size_t)gr*K + kb + lk4, a0,a1,a2,a3);
      As[lk4][lrow]=a0; As[lk4+1][lrow]=a1; As[lk4+2][lrow]=a2; As[lk4+3][lrow]=a3;
    } else {
      As[lk4][lrow]=0.f; As[lk4+1][lrow]=0.f; As[lk4+2][lrow]=0.f; As[lk4+3][lrow]=0.f;
    }
    { float c0,c1,c2,c3; ld4(B + (size_t)(col0+lrow)*K + kb + lk4, c0,c1,c2,c3);
      Bs[lk4][lrow]=c0; Bs[lk4+1][lrow]=c1; Bs[lk4+2][lrow]=c2; Bs[lk4+3][lrow]=c3; }
    __syncthreads();
    #pragma unroll
    for (int kk=0;kk<16;++kk){
      float4 a4 = *reinterpret_cast<const float4*>(&As[kk][ty*4]);
      float4 b4 = *reinterpret_cast<const float4*>(&Bs[kk][tx*4]);
      float av[4]={a4.x,a4.y,a4.z,a4.w};
      float bw[4]={b4.x,b4.y,b4.z,b4.w};
      #pragma unroll
      for (int u=0;u<4;++u)
        #pragma unroll
        for (int v=0;v<4;++v) acc[u][v] += av[u]*bw[v];
    }
    __syncthreads();
  }
  #pragma unroll
  for (int u=0;u<4;++u){
    int gi = row0 + ty*4 + u;
    if (gi >= M) continue;
    #pragma unroll
    for (int v=0;v<4;++v){
      int gj = col0 + tx*4 + v;
      float r = res ? res[(size_t)gi*N+gj] : 0.f;
      float bb = bias ? bias[gj] : 0.f;
      C[(size_t)gi*N+gj] = r + acc[u][v] + bb;
    }
  }
}

// ================= MFMA bf16 GEMM, 128x128 tile, 2x BK=32 per barrier =================
// MODE 0 (QKV): +bias -> bf16 | MODE 1 (WO): +bias+res -> f32
// MODE 2 (HEADS): sum_e r_e(acc+bias_e), qgelu -> bf16 | MODE 3 (TAILS): sum_e r_e(acc+bias_e)+res -> f32
template<int MODE>
__global__ __launch_bounds__(256, (MODE>=2)?2:3) void gemm_mfma(
    const bf16* __restrict__ A, const bf16* __restrict__ B,
    const float* __restrict__ bias, const float* __restrict__ rmat,
    const float* __restrict__ res, float* __restrict__ outf,
    bf16* __restrict__ outb, int M, int N, int K)
{
  constexpr int NE = (MODE>=2) ? 5 : 1;
  __shared__ __align__(16) bf16 As0[4096];
  __shared__ __align__(16) bf16 As1[4096];
  __shared__ __align__(16) bf16 Bs0[4096];
  __shared__ __align__(16) bf16 Bs1[4096];
  __shared__ float rls[(MODE>=2) ? 640 : 4];

  int tid=threadIdx.x, wv=tid>>6, ln=tid&63;
  int quad=ln>>4, mrow=ln&15;
  int row0=blockIdx.y*128, col0=blockIdx.x*128;
  int wr=wv>>1, wc=wv&1;

  if (MODE>=2){
    for (int i=tid; i<640; i+=256) rls[i] = rmat[(size_t)row0*5 + i];
  }

  int c0 = wv*64 + ln;
  int r0 = c0>>2, cc=(c0&3)*8;

  int aoff[4], boff[4];
  #pragma unroll
  for (int i=0;i<4;++i){
    aoff[i] = (wr*64 + i*16 + mrow)*32 + quad*8;
    boff[i] = (wc*64 + i*16 + mrow)*32 + quad*8;
  }

  float tot[4][4][4];
  if (MODE>=2){
    #pragma unroll
    for (int i=0;i<4;++i)
      #pragma unroll
      for (int j=0;j<4;++j)
        #pragma unroll
        for (int r=0;r<4;++r) tot[i][j][r]=0.f;
  }
  f32x4 acc[4][4];
  const f32x4 zero = {0.f,0.f,0.f,0.f};

  for (int e=0;e<NE;++e){
    const bf16* Be = B + (size_t)e*N*K;
    #pragma unroll
    for (int i=0;i<4;++i)
      #pragma unroll
      for (int j=0;j<4;++j) acc[i][j]=zero;

    const bf16* Ab = A + (size_t)(row0+r0)*K + cc;
    const bf16* Bb = Be + (size_t)(col0+r0)*K + cc;
    for (int kb=0; kb<K; kb+=64){
      // chunk 0 (k = kb..kb+31) and chunk 1 (k = kb+32..kb+63), separate buffers
      gload16(Ab + kb,                As0 + wv*512);
      gload16(Ab + (size_t)64*K + kb, As0 + 2048 + wv*512);
      gload16(Bb + kb,                Bs0 + wv*512);
      gload16(Bb + (size_t)64*K + kb, Bs0 + 2048 + wv*512);
      gload16(Ab + kb + 32,                As1 + wv*512);
      gload16(Ab + (size_t)64*K + kb + 32, As1 + 2048 + wv*512);
      gload16(Bb + kb + 32,                Bs1 + wv*512);
      gload16(Bb + (size_t)64*K + kb + 32, Bs1 + 2048 + wv*512);
      __syncthreads();
      short8 af[4], bfr[4];
      #pragma unroll
      for (int i=0;i<4;++i) af[i]  = *reinterpret_cast<const short8*>(As0 + aoff[i]);
      #pragma unroll
      for (int j=0;j<4;++j) bfr[j] = *reinterpret_cast<const short8*>(Bs0 + boff[j]);
      #pragma unroll
      for (int i=0;i<4;++i)
        #pragma unroll
        for (int j=0;j<4;++j)
          acc[i][j] = __builtin_amdgcn_mfma_f32_16x16x32_bf16(af[i], bfr[j], acc[i][j], 0, 0, 0);
      #pragma unroll
      for (int i=0;i<4;++i) af[i]  = *reinterpret_cast<const short8*>(As1 + aoff[i]);
      #pragma unroll
      for (int j=0;j<4;++j) bfr[j] = *reinterpret_cast<const short8*>(Bs1 + boff[j]);
      #pragma unroll
      for (int i=0;i<4;++i)
        #pragma unroll
        for (int j=0;j<4;++j)
          acc[i][j] = __builtin_amdgcn_mfma_f32_16x16x32_bf16(af[i], bfr[j], acc[i][j], 0, 0, 0);
      __syncthreads();
    }
    if (MODE>=2){
      #pragma unroll
      for (int i=0;i<4;++i){
        #pragma unroll
        for (int r=0;r<4;++r){
          int lr = wr*64 + i*16 + quad*4 + r;
          float w = rls[lr*5+e];
          #pragma unroll
          for (int j=0;j<4;++j){
            int gc = col0 + wc*64 + j*16 + mrow;
            tot[i][j][r] += w*(acc[i][j][r] + bias[e*N + gc]);
          }
        }
      }
    }
  }

  #pragma unroll
  for (int i=0;i<4;++i){
    #pragma unroll
    for (int r=0;r<4;++r){
      int gi = row0 + wr*64 + i*16 + quad*4 + r;
      if (gi >= M) continue;
      #pragma unroll
      for (int j=0;j<4;++j){
        int gj = col0 + wc*64 + j*16 + mrow;
        float v;
        if (MODE==0)      v = acc[i][j][r] + bias[gj];
        else if (MODE==1) v = acc[i][j][r] + bias[gj] + res[(size_t)gi*N+gj];
        else if (MODE==2){ float x = tot[i][j][r]; v = x/(1.f+expf(-1.702f*x)); }
        else              v = tot[i][j][r] + res[(size_t)gi*N+gj];
        if (MODE==0 || MODE==2) outb[(size_t)gi*N+gj] = __float2bfloat16(v);
        else                    outf[(size_t)gi*N+gj] = v;
      }
    }
  }
}

extern "C" void kernel_launch(void* const* d_in, const int* in_sizes, int n_in,
                              void* d_out, int out_size, void* d_ws, size_t ws_size,
                              hipStream_t stream) {
  const float* x         = (const float*)d_in[0];
  const float* msg_fc_w  = (const float*)d_in[1];
  const float* msg_fc_b  = (const float*)d_in[2];
  const float* msg_ln_g  = (const float*)d_in[3];
  const float* msg_ln_b  = (const float*)d_in[4];
  const float* msg_wqkv  = (const float*)d_in[5];
  const float* msg_bqkv  = (const float*)d_in[6];
  const float* msg_wo    = (const float*)d_in[7];
  const float* msg_bo    = (const float*)d_in[8];
  const float* attn_wqkv = (const float*)d_in[9];
  const float* attn_bqkv = (const float*)d_in[10];
  const float* attn_wo   = (const float*)d_in[11];
  const float* attn_bo   = (const float*)d_in[12];
  const float* ln1_g     = (const float*)d_in[13];
  const float* ln1_b     = (const float*)d_in[14];
  const float* ln2_g     = (const float*)d_in[15];
  const float* ln2_b     = (const float*)d_in[16];
  const float* cfc_w     = (const float*)d_in[17];
  const float* cfc_b     = (const float*)d_in[18];
  const float* cproj_w   = (const float*)d_in[19];
  const float* cproj_b   = (const float*)d_in[20];
  const float* eh_w      = (const float*)d_in[21];
  const float* eh_b      = (const float*)d_in[22];
  const float* et_w      = (const float*)d_in[23];
  const float* et_b      = (const float*)d_in[24];
  const float* r1_w      = (const float*)d_in[25];
  const float* r1_b      = (const float*)d_in[26];
  const float* r2_w      = (const float*)d_in[27];
  const float* r2_b      = (const float*)d_in[28];
  float* out = (float*)d_out;

  // ---- workspace layout (float units) ----
  float* ws     = (float*)d_ws;
  float* xc     = ws;                        // 6336*768 f32
  float* bigA   = xc + 4866048;
  bf16*  qkv_b  = (bf16*)bigA;               // qkv: 6400*2304 bf16
  bf16*  oh_b   = (bf16*)bigA;               // oh : 6400*3072 bf16 (reuse)
  float* lnbf   = bigA + 9830400;
  bf16*  lnb_b  = (bf16*)lnbf;
  float* attnof = lnbf + 2457600;
  bf16*  attno_b= (bf16*)attnof;
  float* wqf    = attnof + 2457600;
  bf16*  wq_b   = (bf16*)wqf;
  float* wof    = wqf + 884736;
  bf16*  wo_b   = (bf16*)wof;
  float* whf    = wof + 294912;
  bf16*  wh_b   = (bf16*)whf;
  float* wtf    = whf + 5898240;
  bf16*  wt_b   = (bf16*)wtf;
  float* bias_h = wtf + 5898240;
  float* bias_t = bias_h + 15360;
  float* r1b    = bias_t + 3840;
  float* r2b    = r1b + 32000;
  float* msg    = r2b + 32000;
  float* mln    = msg + 24576;
  float* mqkv   = mln + 24576;
  float* matt   = mqkv + 73728;

  // ---- fused weight prep (fp32->bf16, 25.95M elems) + bias concat ----
  prep_weights<<<dim3(6488064/256), 256, 0, stream>>>(
      attn_wqkv, attn_wo, cfc_w, eh_w, cproj_w, et_w,
      wq_b, wo_b, wh_b, wh_b + 2359296, wt_b, wt_b + 2359296);
  prep_bias<<<dim3(75), 256, 0, stream>>>(cfc_b, eh_b, cproj_b, et_b, bias_h, bias_t);

  // 1. xc[0:6304] = x
  hipMemcpyAsync(xc, x, (size_t)4841472*sizeof(float), hipMemcpyDeviceToDevice, stream);
  // 2. msg branch (fp32, tiny)
  gemm_nt<<<dim3(12,1), 256, 0, stream>>>(x, msg_fc_w, msg_fc_b, nullptr, msg, 32, 768, 768);
  ln_rows<<<dim3(32), 256, 0, stream>>>(msg, msg_ln_g, msg_ln_b, mln);
  gemm_nt<<<dim3(36,1), 256, 0, stream>>>(mln, msg_wqkv, msg_bqkv, nullptr, mqkv, 32, 2304, 768);
  msg_attn<<<dim3(48), 64, 0, stream>>>(mqkv, matt);
  gemm_nt<<<dim3(12,1), 256, 0, stream>>>(matt, msg_wo, msg_bo, msg, xc + (size_t)6304*768, 32, 768, 768);
  // 3. ln1 (6336 rows) -> bf16
  ln_rows_b<<<dim3(6336), 256, 0, stream>>>(xc, ln1_g, ln1_b, lnb_b);
  // 4. qkv = ln1 @ Wqkv^T + b (MFMA)
  gemm_mfma<0><<<dim3(18,50), 256, 0, stream>>>(lnb_b, wq_b, attn_bqkv, nullptr, nullptr, nullptr, qkv_b, 6336, 2304, 768);
  // 5. MFMA attention
  attn_mfma<<<dim3(384,4), 256, 0, stream>>>(qkv_b, attno_b);
  // 6. xc += attno @ Wo^T + bo (MFMA)
  gemm_mfma<1><<<dim3(6,50), 256, 0, stream>>>(attno_b, wo_b, attn_bo, nullptr, xc, xc, nullptr, 6336, 768, 768);
  // 7. ln2 (6304 rows) -> bf16
  ln_rows_b<<<dim3(6304), 256, 0, stream>>>(xc, ln2_g, ln2_b, lnb_b);
  // 8. r1 router
  router2<768><<<dim3(1576), 256, 0, stream>>>(lnb_b, r1_w, r1_b, r1b, 6304);
  // 9. heads MoE GEMM -> oh (bf16, qgelu)
  gemm_mfma<2><<<dim3(24,50), 256, 0, stream>>>(lnb_b, wh_b, bias_h, r1b, nullptr, nullptr, oh_b, 6304, 3072, 768);
  // 10. r2 router (K=3072)
  router2<3072><<<dim3(1576), 256, 0, stream>>>(oh_b, r2_w, r2_b, r2b, 6304);
  // 11. tails MoE GEMM + residual -> out (f32)
  gemm_mfma<3><<<dim3(6,50), 256, 0, stream>>>(oh_b, wt_b, bias_t, r2b, xc, out, nullptr, 6304, 768, 3072);
}

// Round 6
// 1209.209 us; speedup vs baseline: 4.8092x; 1.0084x over previous
//
#include <hip/hip_runtime.h>
#include <hip/hip_bf16.h>

typedef __hip_bfloat16 bf16;
typedef __attribute__((ext_vector_type(8))) short short8;
typedef __attribute__((ext_vector_type(4))) float f32x4;

__device__ __forceinline__ float b2f(bf16 v){ return __bfloat162float(v); }
__device__ __forceinline__ unsigned short f2bits(float v){
  bf16 h = __float2bfloat16(v);
  return *reinterpret_cast<unsigned short*>(&h);
}

__device__ __forceinline__ void gload16(const bf16* g, bf16* l){
  __builtin_amdgcn_global_load_lds((const __attribute__((address_space(1))) void*)g,
                                   (__attribute__((address_space(3))) void*)l, 16, 0, 0);
}

__device__ __forceinline__ void ld4(const float* p, float& a,float& b,float& c,float& d){
  float4 v = *reinterpret_cast<const float4*>(p); a=v.x; b=v.y; c=v.z; d=v.w;
}
__device__ __forceinline__ float wave_sum(float v){
  #pragma unroll
  for (int off=32; off>0; off>>=1) v += __shfl_down(v, off);
  return v;
}

// ---------------- fused weight prep: fp32 -> bf16 for 6 weight tensors ----------------
__global__ __launch_bounds__(256) void prep_weights(
    const float* __restrict__ s0, const float* __restrict__ s1,
    const float* __restrict__ s2, const float* __restrict__ s3,
    const float* __restrict__ s4, const float* __restrict__ s5,
    bf16* __restrict__ d0, bf16* __restrict__ d1, bf16* __restrict__ d2,
    bf16* __restrict__ d3, bf16* __restrict__ d4, bf16* __restrict__ d5){
  long i4 = (long)blockIdx.x*256 + threadIdx.x;
  const float* s; bf16* d; long base;
  if      (i4 <  442368){ s=s0; d=d0; base=0; }
  else if (i4 <  589824){ s=s1; d=d1; base=442368; }
  else if (i4 < 1179648){ s=s2; d=d2; base=589824; }
  else if (i4 < 3538944){ s=s3; d=d3; base=1179648; }
  else if (i4 < 4128768){ s=s4; d=d4; base=3538944; }
  else                  { s=s5; d=d5; base=4128768; }
  long j = (i4 - base)*4;
  float4 v = *reinterpret_cast<const float4*>(s + j);
  d[j]   = __float2bfloat16(v.x);
  d[j+1] = __float2bfloat16(v.y);
  d[j+2] = __float2bfloat16(v.z);
  d[j+3] = __float2bfloat16(v.w);
}

// ---------------- fused bias concat (f32 copies) ----------------
__global__ __launch_bounds__(256) void prep_bias(
    const float* __restrict__ cfc_b, const float* __restrict__ eh_b,
    const float* __restrict__ cproj_b, const float* __restrict__ et_b,
    float* __restrict__ bias_h, float* __restrict__ bias_t){
  int i = blockIdx.x*256 + threadIdx.x;
  if (i < 3072)       bias_h[i] = cfc_b[i];
  else if (i < 15360) bias_h[i] = eh_b[i-3072];
  else if (i < 16128) bias_t[i-15360] = cproj_b[i-15360];
  else if (i < 19200) bias_t[i-15360] = et_b[i-16128];
}

// ---------------- zero fill (vec4) ----------------
__global__ __launch_bounds__(256) void zfill(float* __restrict__ p, int n4){
  int i = blockIdx.x*256 + threadIdx.x;
  if (i < n4){ float4 z = {0.f,0.f,0.f,0.f}; *reinterpret_cast<float4*>(p + (size_t)i*4) = z; }
}

// ---------------- qgelu + cvt: f32 partial -> bf16 oh ----------------
__global__ __launch_bounds__(256) void qgelu_cvt(const float* __restrict__ in,
    bf16* __restrict__ out, int n4){
  int i = blockIdx.x*256 + threadIdx.x;
  if (i < n4){
    float4 v = *reinterpret_cast<const float4*>(in + (size_t)i*4);
    float r[4] = {v.x, v.y, v.z, v.w};
    #pragma unroll
    for (int j=0;j<4;++j){ float x=r[j]; r[j] = x/(1.f+__expf(-1.702f*x)); }
    size_t o = (size_t)i*4;
    out[o]   = __float2bfloat16(r[0]);
    out[o+1] = __float2bfloat16(r[1]);
    out[o+2] = __float2bfloat16(r[2]);
    out[o+3] = __float2bfloat16(r[3]);
  }
}

// ---------------- row LayerNorm: fp32 in, fp32 out ----------------
__global__ __launch_bounds__(256) void ln_rows(const float* __restrict__ in,
    const float* __restrict__ g, const float* __restrict__ b,
    float* __restrict__ out){
  int row = blockIdx.x;
  const float* x = in + (size_t)row*768;
  float* o = out + (size_t)row*768;
  float s=0.f, s2=0.f;
  for (int d=threadIdx.x; d<768; d+=256){ float v=x[d]; s+=v; s2+=v*v; }
  s = wave_sum(s); s2 = wave_sum(s2);
  __shared__ float red[8];
  __shared__ float stat[2];
  int lane = threadIdx.x & 63, wid = threadIdx.x >> 6;
  if (lane==0){ red[wid]=s; red[4+wid]=s2; }
  __syncthreads();
  if (threadIdx.x==0){
    float S=red[0]+red[1]+red[2]+red[3];
    float S2=red[4]+red[5]+red[6]+red[7];
    float m = S*(1.f/768.f);
    float var = S2*(1.f/768.f) - m*m;
    stat[0]=m; stat[1]=rsqrtf(var + 1e-5f);
  }
  __syncthreads();
  float m=stat[0], inv=stat[1];
  for (int d=threadIdx.x; d<768; d+=256)
    o[d] = (x[d]-m)*inv*g[d] + b[d];
}

// ---------------- row LayerNorm: fp32 in, bf16 out ----------------
__global__ __launch_bounds__(256) void ln_rows_b(const float* __restrict__ in,
    const float* __restrict__ g, const float* __restrict__ b,
    bf16* __restrict__ out){
  int row = blockIdx.x;
  const float* x = in + (size_t)row*768;
  bf16* o = out + (size_t)row*768;
  float s=0.f, s2=0.f;
  for (int d=threadIdx.x; d<768; d+=256){ float v=x[d]; s+=v; s2+=v*v; }
  s = wave_sum(s); s2 = wave_sum(s2);
  __shared__ float red[8];
  __shared__ float stat[2];
  int lane = threadIdx.x & 63, wid = threadIdx.x >> 6;
  if (lane==0){ red[wid]=s; red[4+wid]=s2; }
  __syncthreads();
  if (threadIdx.x==0){
    float S=red[0]+red[1]+red[2]+red[3];
    float S2=red[4]+red[5]+red[6]+red[7];
    float m = S*(1.f/768.f);
    float var = S2*(1.f/768.f) - m*m;
    stat[0]=m; stat[1]=rsqrtf(var + 1e-5f);
  }
  __syncthreads();
  float m=stat[0], inv=stat[1];
  for (int d=threadIdx.x; d<768; d+=256)
    o[d] = __float2bfloat16((x[d]-m)*inv*g[d] + b[d]);
}

// ---------------- router: one wave per row, x cached in registers ----------------
template<int K>
__global__ __launch_bounds__(256) void router2(const bf16* __restrict__ X,
    const float* __restrict__ W, const float* __restrict__ bias,
    float* __restrict__ out, int rows){
  int row = blockIdx.x*4 + (threadIdx.x>>6);
  int lane = threadIdx.x & 63;
  if (row >= rows) return;
  const bf16* x = X + (size_t)row*K;
  constexpr int NC = K/64;
  float xa[NC];
  #pragma unroll
  for (int c=0;c<NC;++c) xa[c] = b2f(x[c*64 + lane]);
  float lg[5];
  #pragma unroll
  for (int e=0;e<5;++e){
    const float* w = W + (size_t)e*K;
    float p=0.f;
    #pragma unroll
    for (int c=0;c<NC;++c) p += xa[c]*w[c*64 + lane];
    lg[e] = wave_sum(p);
  }
  if (lane==0){
    float mx=-1e30f;
    #pragma unroll
    for (int e=0;e<5;++e){ lg[e] += bias[e]; mx = fmaxf(mx, lg[e]); }
    float s=0.f;
    #pragma unroll
    for (int e=0;e<5;++e){ lg[e]=expf(lg[e]-mx); s+=lg[e]; }
    float inv=1.f/s;
    #pragma unroll
    for (int e=0;e<5;++e) out[(size_t)row*5+e] = lg[e]*inv;
  }
}

// ---------------- msg attention: seq=8 within each b, 12 heads (fp32) ----------------
__global__ __launch_bounds__(64) void msg_attn(const float* __restrict__ mqkv,
    float* __restrict__ mattno){
  int bh = blockIdx.x; int b = bh/12, h = bh%12;
  __shared__ float qs[8][64], ks[8][64], vs[8][64], sc[8][8];
  int lane = threadIdx.x;
  for (int i=lane; i<512; i+=64){
    int t=i>>6, d=i&63;
    size_t base = ((size_t)(b*8+t))*2304 + h*64 + d;
    qs[t][d]=mqkv[base]; ks[t][d]=mqkv[base+768]; vs[t][d]=mqkv[base+1536];
  }
  __syncthreads();
  { int t=lane>>3, m=lane&7; float a=0.f;
    #pragma unroll
    for (int d=0;d<64;++d) a += qs[t][d]*ks[m][d];
    sc[t][m] = a*0.125f; }
  __syncthreads();
  if (lane<8){
    int t=lane; float mx=-1e30f;
    #pragma unroll
    for (int m=0;m<8;++m) mx=fmaxf(mx, sc[t][m]);
    float s=0.f;
    #pragma unroll
    for (int m=0;m<8;++m){ float e=expf(sc[t][m]-mx); sc[t][m]=e; s+=e; }
    float inv=1.f/s;
    #pragma unroll
    for (int m=0;m<8;++m) sc[t][m]*=inv;
  }
  __syncthreads();
  { int t=lane>>3, d0=(lane&7)*8;
    for (int dd=0; dd<8; ++dd){
      int d=d0+dd; float a=0.f;
      #pragma unroll
      for (int m=0;m<8;++m) a += sc[t][m]*vs[m][d];
      mattno[((size_t)(b*8+t))*768 + h*64 + d] = a;
    } }
}

// ================ MFMA attention: seq=198, D=64; block = (bb,h) x 64 q-rows ================
__global__ __launch_bounds__(256) void attn_mfma(const bf16* __restrict__ qkv,
    bf16* __restrict__ attno){
  constexpr int KP = 232;
  __shared__ __align__(16) unsigned short Ks[208*72];
  __shared__ __align__(16) unsigned short Vt[64*KP];
  __shared__ __align__(16) unsigned short Ps[4*16*KP];

  int tid = threadIdx.x;
  int bh = blockIdx.x; int bb = bh/12, h = bh%12;
  int l0 = blockIdx.y*64;
  int wv = tid>>6, ln = tid&63, quad = ln>>4, mrow = ln&15;

  for (int i=tid; i<1584; i+=256){
    int m=i>>3, dc=(i&7)<<3;
    const uint4 kv = *reinterpret_cast<const uint4*>(qkv + ((size_t)(m*32+bb))*2304 + 768 + h*64 + dc);
    *reinterpret_cast<uint4*>(Ks + m*72 + dc) = kv;
    const uint4 vv = *reinterpret_cast<const uint4*>(qkv + ((size_t)(m*32+bb))*2304 + 1536 + h*64 + dc);
    unsigned int w[4] = {vv.x, vv.y, vv.z, vv.w};
    #pragma unroll
    for (int j=0;j<4;++j){
      Vt[(dc+2*j  )*KP + m] = (unsigned short)(w[j] & 0xffff);
      Vt[(dc+2*j+1)*KP + m] = (unsigned short)(w[j] >> 16);
    }
  }
  for (int i=tid; i<10*72; i+=256) Ks[198*72 + i] = 0;
  for (int i=tid; i<64*34; i+=256){ int d=i/34, c=198+(i%34); Vt[d*KP+c] = 0; }
  { unsigned int* pz = reinterpret_cast<unsigned int*>(Ps);
    for (int i=tid; i<4*16*KP/2; i+=256) pz[i] = 0; }

  int ql = l0 + wv*16 + mrow;
  short8 aq[2] = { {0,0,0,0,0,0,0,0}, {0,0,0,0,0,0,0,0} };
  if (ql < 198){
    aq[0] = *reinterpret_cast<const short8*>(qkv + ((size_t)(ql*32+bb))*2304 + h*64 + quad*8);
    aq[1] = *reinterpret_cast<const short8*>(qkv + ((size_t)(ql*32+bb))*2304 + h*64 + 32 + quad*8);
  }
  __syncthreads();

  f32x4 sc[13];
  const f32x4 zero = {0.f,0.f,0.f,0.f};
  #pragma unroll
  for (int t=0;t<13;++t){
    const short8 bk0 = *reinterpret_cast<const short8*>(Ks + (t*16+mrow)*72 + quad*8);
    const short8 bk1 = *reinterpret_cast<const short8*>(Ks + (t*16+mrow)*72 + 32 + quad*8);
    f32x4 a = zero;
    a = __builtin_amdgcn_mfma_f32_16x16x32_bf16(aq[0], bk0, a, 0,0,0);
    a = __builtin_amdgcn_mfma_f32_16x16x32_bf16(aq[1], bk1, a, 0,0,0);
    sc[t] = a * 0.125f;
  }
  if (192 + mrow >= 198) sc[12] = (f32x4){-1e30f,-1e30f,-1e30f,-1e30f};

  float inv[4];
  #pragma unroll
  for (int r=0;r<4;++r){
    float m = -1e30f;
    #pragma unroll
    for (int t=0;t<13;++t) m = fmaxf(m, sc[t][r]);
    #pragma unroll
    for (int msk=1; msk<16; msk<<=1) m = fmaxf(m, __shfl_xor(m, msk));
    float s = 0.f;
    #pragma unroll
    for (int t=0;t<13;++t){ float e = __expf(sc[t][r]-m); sc[t][r]=e; s+=e; }
    #pragma unroll
    for (int msk=1; msk<16; msk<<=1) s += __shfl_xor(s, msk);
    inv[r] = 1.f/s;
  }

  #pragma unroll
  for (int t=0;t<13;++t)
    #pragma unroll
    for (int r=0;r<4;++r)
      Ps[(wv*16 + quad*4+r)*KP + t*16+mrow] = f2bits(sc[t][r]);
  __syncthreads();

  f32x4 o[4] = {zero,zero,zero,zero};
  #pragma unroll
  for (int kc=0;kc<7;++kc){
    const short8 ap = *reinterpret_cast<const short8*>(Ps + (wv*16+mrow)*KP + kc*32 + quad*8);
    #pragma unroll
    for (int nt=0;nt<4;++nt){
      const short8 bv = *reinterpret_cast<const short8*>(Vt + (nt*16+mrow)*KP + kc*32 + quad*8);
      o[nt] = __builtin_amdgcn_mfma_f32_16x16x32_bf16(ap, bv, o[nt], 0,0,0);
    }
  }
  #pragma unroll
  for (int r=0;r<4;++r){
    int l = l0 + wv*16 + quad*4 + r;
    if (l >= 198) continue;
    #pragma unroll
    for (int nt=0;nt<4;++nt){
      int d = nt*16 + mrow;
      attno[((size_t)(l*32+bb))*768 + h*64 + d] = __float2bfloat16(o[nt][r]*inv[r]);
    }
  }
}

// ---------------- small fp32 tiled GEMM for msg branch ----------------
__global__ __launch_bounds__(256) void gemm_nt(const float* __restrict__ A,
    const float* __restrict__ B, const float* __restrict__ bias,
    const float* res, float* C,
    int M, int N, int K){
  __shared__ __align__(16) float As[16][68];
  __shared__ __align__(16) float Bs[16][68];
  int tid=threadIdx.x, tx=tid&15, ty=tid>>4;
  int row0=blockIdx.y*64, col0=blockIdx.x*64;
  int lrow=tid>>2, lk4=(tid&3)*4;
  float acc[4][4]={};
  for (int kb=0; kb<K; kb+=16){
    int gr = row0 + lrow;
    if (gr < M){
      float a0,a1,a2,a3; ld4(A + (size_t)gr*K + kb + lk4, a0,a1,a2,a3);
      As[lk4][lrow]=a0; As[lk4+1][lrow]=a1; As[lk4+2][lrow]=a2; As[lk4+3][lrow]=a3;
    } else {
      As[lk4][lrow]=0.f; As[lk4+1][lrow]=0.f; As[lk4+2][lrow]=0.f; As[lk4+3][lrow]=0.f;
    }
    { float c0,c1,c2,c3; ld4(B + (size_t)(col0+lrow)*K + kb + lk4, c0,c1,c2,c3);
      Bs[lk4][lrow]=c0; Bs[lk4+1][lrow]=c1; Bs[lk4+2][lrow]=c2; Bs[lk4+3][lrow]=c3; }
    __syncthreads();
    #pragma unroll
    for (int kk=0;kk<16;++kk){
      float4 a4 = *reinterpret_cast<const float4*>(&As[kk][ty*4]);
      float4 b4 = *reinterpret_cast<const float4*>(&Bs[kk][tx*4]);
      float av[4]={a4.x,a4.y,a4.z,a4.w};
      float bw[4]={b4.x,b4.y,b4.z,b4.w};
      #pragma unroll
      for (int u=0;u<4;++u)
        #pragma unroll
        for (int v=0;v<4;++v) acc[u][v] += av[u]*bw[v];
    }
    __syncthreads();
  }
  #pragma unroll
  for (int u=0;u<4;++u){
    int gi = row0 + ty*4 + u;
    if (gi >= M) continue;
    #pragma unroll
    for (int v=0;v<4;++v){
      int gj = col0 + tx*4 + v;
      float r = res ? res[(size_t)gi*N+gj] : 0.f;
      float bb = bias ? bias[gj] : 0.f;
      C[(size_t)gi*N+gj] = r + acc[u][v] + bb;
    }
  }
}

// ================= MFMA bf16 GEMM, 128x128 tile, 2x BK=32 per barrier =================
// MODE 0 (QKV): +bias -> bf16 | MODE 1 (WO): +bias+res -> f32
template<int MODE>
__global__ __launch_bounds__(256,3) void gemm_mfma(
    const bf16* __restrict__ A, const bf16* __restrict__ B,
    const float* __restrict__ bias,
    const float* res, float* __restrict__ outf,
    bf16* __restrict__ outb, int M, int N, int K)
{
  __shared__ __align__(16) bf16 As0[4096];
  __shared__ __align__(16) bf16 As1[4096];
  __shared__ __align__(16) bf16 Bs0[4096];
  __shared__ __align__(16) bf16 Bs1[4096];

  int tid=threadIdx.x, wv=tid>>6, ln=tid&63;
  int quad=ln>>4, mrow=ln&15;
  int row0=blockIdx.y*128, col0=blockIdx.x*128;
  int wr=wv>>1, wc=wv&1;

  int c0 = wv*64 + ln;
  int r0 = c0>>2, cc=(c0&3)*8;

  int aoff[4], boff[4];
  #pragma unroll
  for (int i=0;i<4;++i){
    aoff[i] = (wr*64 + i*16 + mrow)*32 + quad*8;
    boff[i] = (wc*64 + i*16 + mrow)*32 + quad*8;
  }

  f32x4 acc[4][4];
  const f32x4 zero = {0.f,0.f,0.f,0.f};
  #pragma unroll
  for (int i=0;i<4;++i)
    #pragma unroll
    for (int j=0;j<4;++j) acc[i][j]=zero;

  const bf16* Ab = A + (size_t)(row0+r0)*K + cc;
  const bf16* Bb = B + (size_t)(col0+r0)*K + cc;
  for (int kb=0; kb<K; kb+=64){
    gload16(Ab + kb,                As0 + wv*512);
    gload16(Ab + (size_t)64*K + kb, As0 + 2048 + wv*512);
    gload16(Bb + kb,                Bs0 + wv*512);
    gload16(Bb + (size_t)64*K + kb, Bs0 + 2048 + wv*512);
    gload16(Ab + kb + 32,                As1 + wv*512);
    gload16(Ab + (size_t)64*K + kb + 32, As1 + 2048 + wv*512);
    gload16(Bb + kb + 32,                Bs1 + wv*512);
    gload16(Bb + (size_t)64*K + kb + 32, Bs1 + 2048 + wv*512);
    __syncthreads();
    short8 af[4], bfr[4];
    #pragma unroll
    for (int i=0;i<4;++i) af[i]  = *reinterpret_cast<const short8*>(As0 + aoff[i]);
    #pragma unroll
    for (int j=0;j<4;++j) bfr[j] = *reinterpret_cast<const short8*>(Bs0 + boff[j]);
    #pragma unroll
    for (int i=0;i<4;++i)
      #pragma unroll
      for (int j=0;j<4;++j)
        acc[i][j] = __builtin_amdgcn_mfma_f32_16x16x32_bf16(af[i], bfr[j], acc[i][j], 0, 0, 0);
    #pragma unroll
    for (int i=0;i<4;++i) af[i]  = *reinterpret_cast<const short8*>(As1 + aoff[i]);
    #pragma unroll
    for (int j=0;j<4;++j) bfr[j] = *reinterpret_cast<const short8*>(Bs1 + boff[j]);
    #pragma unroll
    for (int i=0;i<4;++i)
      #pragma unroll
      for (int j=0;j<4;++j)
        acc[i][j] = __builtin_amdgcn_mfma_f32_16x16x32_bf16(af[i], bfr[j], acc[i][j], 0, 0, 0);
    __syncthreads();
  }

  #pragma unroll
  for (int i=0;i<4;++i){
    #pragma unroll
    for (int r=0;r<4;++r){
      int gi = row0 + wr*64 + i*16 + quad*4 + r;
      if (gi >= M) continue;
      #pragma unroll
      for (int j=0;j<4;++j){
        int gj = col0 + wc*64 + j*16 + mrow;
        if (MODE==0) outb[(size_t)gi*N+gj] = __float2bfloat16(acc[i][j][r] + bias[gj]);
        else         outf[(size_t)gi*N+gj] = acc[i][j][r] + bias[gj] + res[(size_t)gi*N+gj];
      }
    }
  }
}

// ================= MoE split GEMM: one expert (and K-chunk) per block, atomic accumulate ====
// part[m,n] += r_e[m] * ( A[m,:]@B_e[n,:] + (k0==0 ? bias_e[n] : 0) )
template<int KSPLIT>
__global__ __launch_bounds__(256,3) void gemm_split(
    const bf16* __restrict__ A, const bf16* __restrict__ B,
    const float* __restrict__ bias, const float* __restrict__ rmat,
    float* __restrict__ part, int M, int N, int K)
{
  __shared__ __align__(16) bf16 As0[4096];
  __shared__ __align__(16) bf16 As1[4096];
  __shared__ __align__(16) bf16 Bs0[4096];
  __shared__ __align__(16) bf16 Bs1[4096];

  int e  = blockIdx.z / KSPLIT;
  int k0 = (blockIdx.z % KSPLIT) * (K/KSPLIT);
  int Kb = K/KSPLIT;
  const bf16* Be = B + (size_t)e*N*K;

  int tid=threadIdx.x, wv=tid>>6, ln=tid&63;
  int quad=ln>>4, mrow=ln&15;
  int row0=blockIdx.y*128, col0=blockIdx.x*128;
  int wr=wv>>1, wc=wv&1;

  int c0 = wv*64 + ln;
  int r0 = c0>>2, cc=(c0&3)*8;

  int aoff[4], boff[4];
  #pragma unroll
  for (int i=0;i<4;++i){
    aoff[i] = (wr*64 + i*16 + mrow)*32 + quad*8;
    boff[i] = (wc*64 + i*16 + mrow)*32 + quad*8;
  }

  f32x4 acc[4][4];
  const f32x4 zero = {0.f,0.f,0.f,0.f};
  #pragma unroll
  for (int i=0;i<4;++i)
    #pragma unroll
    for (int j=0;j<4;++j) acc[i][j]=zero;

  const bf16* Ab = A  + (size_t)(row0+r0)*K + k0 + cc;
  const bf16* Bb = Be + (size_t)(col0+r0)*K + k0 + cc;
  for (int kb=0; kb<Kb; kb+=64){
    gload16(Ab + kb,                As0 + wv*512);
    gload16(Ab + (size_t)64*K + kb, As0 + 2048 + wv*512);
    gload16(Bb + kb,                Bs0 + wv*512);
    gload16(Bb + (size_t)64*K + kb, Bs0 + 2048 + wv*512);
    gload16(Ab + kb + 32,                As1 + wv*512);
    gload16(Ab + (size_t)64*K + kb + 32, As1 + 2048 + wv*512);
    gload16(Bb + kb + 32,                Bs1 + wv*512);
    gload16(Bb + (size_t)64*K + kb + 32, Bs1 + 2048 + wv*512);
    __syncthreads();
    short8 af[4], bfr[4];
    #pragma unroll
    for (int i=0;i<4;++i) af[i]  = *reinterpret_cast<const short8*>(As0 + aoff[i]);
    #pragma unroll
    for (int j=0;j<4;++j) bfr[j] = *reinterpret_cast<const short8*>(Bs0 + boff[j]);
    #pragma unroll
    for (int i=0;i<4;++i)
      #pragma unroll
      for (int j=0;j<4;++j)
        acc[i][j] = __builtin_amdgcn_mfma_f32_16x16x32_bf16(af[i], bfr[j], acc[i][j], 0, 0, 0);
    #pragma unroll
    for (int i=0;i<4;++i) af[i]  = *reinterpret_cast<const short8*>(As1 + aoff[i]);
    #pragma unroll
    for (int j=0;j<4;++j) bfr[j] = *reinterpret_cast<const short8*>(Bs1 + boff[j]);
    #pragma unroll
    for (int i=0;i<4;++i)
      #pragma unroll
      for (int j=0;j<4;++j)
        acc[i][j] = __builtin_amdgcn_mfma_f32_16x16x32_bf16(af[i], bfr[j], acc[i][j], 0, 0, 0);
    __syncthreads();
  }

  // row weights r_e[m] for this lane's 16 rows
  float rw[4][4];
  #pragma unroll
  for (int i=0;i<4;++i)
    #pragma unroll
    for (int r=0;r<4;++r){
      int gi = row0 + wr*64 + i*16 + quad*4 + r;
      rw[i][r] = (gi < M) ? rmat[(size_t)gi*5 + e] : 0.f;
    }

  #pragma unroll
  for (int i=0;i<4;++i){
    #pragma unroll
    for (int r=0;r<4;++r){
      int gi = row0 + wr*64 + i*16 + quad*4 + r;
      if (gi >= M) continue;
      #pragma unroll
      for (int j=0;j<4;++j){
        int gj = col0 + wc*64 + j*16 + mrow;
        float v = acc[i][j][r];
        if (k0 == 0) v += bias[e*N + gj];
        atomicAdd(&part[(size_t)gi*N + gj], rw[i][r]*v);
      }
    }
  }
}

extern "C" void kernel_launch(void* const* d_in, const int* in_sizes, int n_in,
                              void* d_out, int out_size, void* d_ws, size_t ws_size,
                              hipStream_t stream) {
  const float* x         = (const float*)d_in[0];
  const float* msg_fc_w  = (const float*)d_in[1];
  const float* msg_fc_b  = (const float*)d_in[2];
  const float* msg_ln_g  = (const float*)d_in[3];
  const float* msg_ln_b  = (const float*)d_in[4];
  const float* msg_wqkv  = (const float*)d_in[5];
  const float* msg_bqkv  = (const float*)d_in[6];
  const float* msg_wo    = (const float*)d_in[7];
  const float* msg_bo    = (const float*)d_in[8];
  const float* attn_wqkv = (const float*)d_in[9];
  const float* attn_bqkv = (const float*)d_in[10];
  const float* attn_wo   = (const float*)d_in[11];
  const float* attn_bo   = (const float*)d_in[12];
  const float* ln1_g     = (const float*)d_in[13];
  const float* ln1_b     = (const float*)d_in[14];
  const float* ln2_g     = (const float*)d_in[15];
  const float* ln2_b     = (const float*)d_in[16];
  const float* cfc_w     = (const float*)d_in[17];
  const float* cfc_b     = (const float*)d_in[18];
  const float* cproj_w   = (const float*)d_in[19];
  const float* cproj_b   = (const float*)d_in[20];
  const float* eh_w      = (const float*)d_in[21];
  const float* eh_b      = (const float*)d_in[22];
  const float* et_w      = (const float*)d_in[23];
  const float* et_b      = (const float*)d_in[24];
  const float* r1_w      = (const float*)d_in[25];
  const float* r1_b      = (const float*)d_in[26];
  const float* r2_w      = (const float*)d_in[27];
  const float* r2_b      = (const float*)d_in[28];
  float* out = (float*)d_out;

  // ---- workspace layout (float units) ----
  float* ws     = (float*)d_ws;
  float* xc     = ws;                        // 6336*768 f32
  float* bigA   = xc + 4866048;
  bf16*  qkv_b  = (bf16*)bigA;               // qkv: 6400*2304 bf16
  bf16*  oh_b   = (bf16*)bigA;               // oh : 6400*3072 bf16 (reuse)
  float* lnbf   = bigA + 9830400;
  bf16*  lnb_b  = (bf16*)lnbf;
  float* attnof = lnbf + 2457600;
  bf16*  attno_b= (bf16*)attnof;
  float* wqf    = attnof + 2457600;
  bf16*  wq_b   = (bf16*)wqf;
  float* wof    = wqf + 884736;
  bf16*  wo_b   = (bf16*)wof;
  float* whf    = wof + 294912;
  bf16*  wh_b   = (bf16*)whf;
  float* wtf    = whf + 5898240;
  bf16*  wt_b   = (bf16*)wtf;
  float* bias_h = wtf + 5898240;
  float* bias_t = bias_h + 15360;
  float* r1b    = bias_t + 3840;
  float* r2b    = r1b + 32000;
  float* msg    = r2b + 32000;
  float* mln    = msg + 24576;
  float* mqkv   = mln + 24576;
  float* matt   = mqkv + 73728;
  float* partH  = matt + 24576;              // 6304*3072 f32 = 19,365,888

  // ---- fused weight prep + bias concat ----
  prep_weights<<<dim3(6488064/256), 256, 0, stream>>>(
      attn_wqkv, attn_wo, cfc_w, eh_w, cproj_w, et_w,
      wq_b, wo_b, wh_b, wh_b + 2359296, wt_b, wt_b + 2359296);
  prep_bias<<<dim3(75), 256, 0, stream>>>(cfc_b, eh_b, cproj_b, et_b, bias_h, bias_t);

  // 1. xc[0:6304] = x
  hipMemcpyAsync(xc, x, (size_t)4841472*sizeof(float), hipMemcpyDeviceToDevice, stream);
  // 2. msg branch (fp32, tiny)
  gemm_nt<<<dim3(12,1), 256, 0, stream>>>(x, msg_fc_w, msg_fc_b, nullptr, msg, 32, 768, 768);
  ln_rows<<<dim3(32), 256, 0, stream>>>(msg, msg_ln_g, msg_ln_b, mln);
  gemm_nt<<<dim3(36,1), 256, 0, stream>>>(mln, msg_wqkv, msg_bqkv, nullptr, mqkv, 32, 2304, 768);
  msg_attn<<<dim3(48), 64, 0, stream>>>(mqkv, matt);
  gemm_nt<<<dim3(12,1), 256, 0, stream>>>(matt, msg_wo, msg_bo, msg, xc + (size_t)6304*768, 32, 768, 768);
  // 3. ln1 (6336 rows) -> bf16
  ln_rows_b<<<dim3(6336), 256, 0, stream>>>(xc, ln1_g, ln1_b, lnb_b);
  // 4. qkv = ln1 @ Wqkv^T + b (MFMA)
  gemm_mfma<0><<<dim3(18,50), 256, 0, stream>>>(lnb_b, wq_b, attn_bqkv, nullptr, nullptr, qkv_b, 6336, 2304, 768);
  // 5. MFMA attention
  attn_mfma<<<dim3(384,4), 256, 0, stream>>>(qkv_b, attno_b);
  // 6. xc += attno @ Wo^T + bo (MFMA)
  gemm_mfma<1><<<dim3(6,50), 256, 0, stream>>>(attno_b, wo_b, attn_bo, xc, xc, nullptr, 6336, 768, 768);
  // 7. ln2 (6304 rows) -> bf16
  ln_rows_b<<<dim3(6304), 256, 0, stream>>>(xc, ln2_g, ln2_b, lnb_b);
  // 8. r1 router
  router2<768><<<dim3(1576), 256, 0, stream>>>(lnb_b, r1_w, r1_b, r1b, 6304);
  // 9a. zero partial, out = residual (for tails later)
  zfill<<<dim3(4841472/256), 256, 0, stream>>>(partH, 4841472);
  hipMemcpyAsync(out, xc, (size_t)4841472*sizeof(float), hipMemcpyDeviceToDevice, stream);
  // 9b. heads: per-expert split, atomic accumulate into partH
  gemm_split<1><<<dim3(24,50,5), 256, 0, stream>>>(lnb_b, wh_b, bias_h, r1b, partH, 6304, 3072, 768);
  // 9c. qgelu + cvt -> oh (bf16)
  qgelu_cvt<<<dim3(4841472/256), 256, 0, stream>>>(partH, oh_b, 4841472);
  // 10. r2 router (K=3072)
  router2<3072><<<dim3(1576), 256, 0, stream>>>(oh_b, r2_w, r2_b, r2b, 6304);
  // 11. tails: per-expert + K-split, atomic accumulate into out (residual preloaded)
  gemm_split<2><<<dim3(6,50,10), 256, 0, stream>>>(oh_b, wt_b, bias_t, r2b, out, 6304, 768, 3072);
}